// Round 3
// baseline (360.167 us; speedup 1.0000x reference)
//
#include <hip/hip_runtime.h>

// GCN forward: 3x GCNConv (128->64->64->2) + linear head (2->16).
// N=100000 nodes, E=1600000 edges (+self-loops handled analytically).
// Preprocessing: two-level LDS bucket sort. Aggregation: atomic-free
// FULL-WAVE segment-sum gathers (lane = channel) over int16 rows with
// per-row scales fused into the transform GEMM; TWO nodes per wave.
// Round 19:
//  - k_seg0t PERSISTENT: grid 2048 (8 blocks/CU), W1 staged to LDS ONCE per
//    block, grid-stride over node pairs (round-18 staged 16KB + barrier in
//    each of 12500 short-lived blocks = 200MB L2->LDS + ramp overhead).
//  - k_gemm128: phase-1 X+W prefetched into 32 VGPRs BEFORE phase-0 compute
//    (async-stage split) -- round-18's 2-phase version stalled at the phase
//    boundary (staging fully exposed, inferred ~52us unchanged vs 1-phase).
//    __launch_bounds__(256,4) pins <=128 VGPR so 4 blocks/CU holds.
//  - k_seg2f: 16-lanes-per-node gather (was: 1 thread/node, 391 blocks =
//    1.5 waves/SIMD, ~16 serial random 8B loads/thread = latency-bound).
//    Now 4 nodes/wave, lane-parallel edge loads, 4-step shfl_xor reduce.
// BANNED (measured failures): half-wave/2-rows-per-load gather (~3e-3 absmax,
// rounds 7-9/11); SGPR-indexed rs[] (s_load thrash, r13); LDS float atomicAdd
// (CAS storm, r15); LDS row pitch not 0 mod 16B in float4 tiles (r17);
// 64-entry per-lane VGPR arrays in gather kernels (occupancy halved, r17).
// dis[] pre-folded: T'[v]=dis[v]*t[v] => O[i]=dis[i]*(T'[i]+sum T'[s])+b.

#define NF 128
#define NH 64
#define NPB 256      // nodes per coarse bucket (bucket = dst >> 8)
#define MAXNB 512    // max coarse buckets (N < 131072, matches 17-bit src pack)
#define CAP 6144     // max edges per coarse bucket (mean 4096, >30 sigma)
#define A1G 1024     // grid for coarse count/scatter (must match between them)

// Zero coarse counters + detect int64 vs int32 edge_index layout.
__global__ void k_init0(const int* __restrict__ ei, int* __restrict__ fmt,
                        int* __restrict__ ccnt, int nb16) {
    int i = blockIdx.x * 256 + threadIdx.x;
    if (i < nb16) ccnt[i] = 0;
    if (i == 0) {
        int f = 1;
        #pragma unroll
        for (int k = 1; k < 32; k += 2) if (ei[k] != 0) f = 0;
        *fmt = f;   // 1 => int64 (stride 2 in int32 words), 0 => int32
    }
}

// Coarse count: LDS histogram per block, then reserve per-(block,bucket) space
// with ONE padded global atomic per bucket per block (line-parallel).
__global__ void __launch_bounds__(256) k_coarse(
        const int* __restrict__ ei, const int* __restrict__ fmt,
        int* __restrict__ ccnt, int* __restrict__ blockbase, int E, int NB) {
    __shared__ int h[MAXNB];
    int sh = *fmt;
    for (int i = threadIdx.x; i < NB; i += 256) h[i] = 0;
    __syncthreads();
    for (long long e = (long long)blockIdx.x * 256 + threadIdx.x; e < E;
         e += (long long)A1G * 256) {
        int d = ei[(long long)(E + e) << sh];
        atomicAdd(&h[d >> 8], 1);
    }
    __syncthreads();
    for (int b = threadIdx.x; b < NB; b += 256) {
        int c = h[b];
        int base = (c > 0) ? atomicAdd(&ccnt[b * 16], c) : 0;
        blockbase[(long long)blockIdx.x * NB + b] = base;
    }
}

// Exclusive scan of the NB coarse counts (single block).
__global__ void __launch_bounds__(512) k_cscan(
        const int* __restrict__ ccnt, int* __restrict__ cstart, int NB) {
    __shared__ int s[512];
    int t = threadIdx.x;
    int c = (t < NB) ? ccnt[t * 16] : 0;
    s[t] = c;
    __syncthreads();
    for (int off = 1; off < 512; off <<= 1) {
        int v = s[t];
        int u = (t >= off) ? s[t - off] : 0;
        __syncthreads();
        s[t] = v + u;
        __syncthreads();
    }
    if (t < NB) cstart[t] = s[t] - c;
}

// Coarse scatter: same grid-stride partition as k_coarse, so this block's
// per-bucket totals equal its reservation. Edge packed as src|(dst&255)<<17.
__global__ void __launch_bounds__(256) k_cscatter(
        const int* __restrict__ ei, const int* __restrict__ fmt,
        const int* __restrict__ cstart, const int* __restrict__ blockbase,
        int* __restrict__ pairs, int E, int NB) {
    __shared__ int h[MAXNB];
    __shared__ int bb[MAXNB];
    int sh = *fmt;
    for (int i = threadIdx.x; i < NB; i += 256) {
        h[i] = 0;
        bb[i] = cstart[i] + blockbase[(long long)blockIdx.x * NB + i];
    }
    __syncthreads();
    for (long long e = (long long)blockIdx.x * 256 + threadIdx.x; e < E;
         e += (long long)A1G * 256) {
        int s = ei[(long long)e << sh];
        int d = ei[(long long)(E + e) << sh];
        int b = d >> 8;
        int r = atomicAdd(&h[b], 1);
        pairs[bb[b] + r] = s | ((d & 255) << 17);
    }
}

// Fine sort: one block per coarse bucket, entirely in LDS. Emits cnt/start/dis
// (coalesced) and esrc (scatter within the bucket's contiguous window).
__global__ void __launch_bounds__(256) k_bucket(
        const int* __restrict__ pairs, const int* __restrict__ ccnt,
        const int* __restrict__ cstart, int* __restrict__ esrc,
        int* __restrict__ cnt, int* __restrict__ start, float* __restrict__ dis,
        int N) {
    __shared__ int words[CAP];
    __shared__ unsigned char rk[CAP];
    __shared__ int h[NPB];
    __shared__ int hs[NPB];
    int b = blockIdx.x;
    int cs = cstart[b];
    int ec = ccnt[b * 16];
    if (ec > CAP) ec = CAP;          // memory-safety clamp (P ~ 0 for uniform dst)
    int t = threadIdx.x;
    for (int i = t; i < ec; i += 256) words[i] = pairs[cs + i];
    h[t] = 0;
    __syncthreads();
    for (int i = t; i < ec; i += 256) {
        int ld = words[i] >> 17;
        rk[i] = (unsigned char)atomicAdd(&h[ld], 1);
    }
    __syncthreads();
    int c = h[t];
    hs[t] = c;
    __syncthreads();
    for (int off = 1; off < 256; off <<= 1) {
        int v = hs[t];
        int u = (t >= off) ? hs[t - off] : 0;
        __syncthreads();
        hs[t] = v + u;               // inclusive scan
        __syncthreads();
    }
    int node = b * NPB + t;
    if (node < N) {
        cnt[node] = c;
        start[node] = cs + hs[t] - c;
        dis[node] = rsqrtf(1.0f + (float)c);   // degree includes self-loop
    }
    for (int i = t; i < ec; i += 256) {
        int w = words[i];
        int ld = w >> 17;
        esrc[cs + (hs[ld] - h[ld]) + rk[i]] = w & 0x1FFFF;
    }
}

// One 16-wide k4 step of the 4x4 register-tile FMA block.
#define GEMM_K4_BODY                                                          \
            float4 xv0 = *(const float4*)(x0 + k4 * 4);                       \
            float4 xv1 = *(const float4*)(x1 + k4 * 4);                       \
            float4 xv2 = *(const float4*)(x2 + k4 * 4);                       \
            float4 xv3 = *(const float4*)(x3 + k4 * 4);                       \
            float4 wa = *(const float4*)(Wp0 + (k4 * 4 + 0) * NH);            \
            float4 wb = *(const float4*)(Wp0 + (k4 * 4 + 1) * NH);            \
            float4 wc = *(const float4*)(Wp0 + (k4 * 4 + 2) * NH);            \
            float4 wd = *(const float4*)(Wp0 + (k4 * 4 + 3) * NH);            \
            a0.x += xv0.x * wa.x; a0.y += xv0.x * wa.y; a0.z += xv0.x * wa.z; a0.w += xv0.x * wa.w; \
            a1.x += xv1.x * wa.x; a1.y += xv1.x * wa.y; a1.z += xv1.x * wa.z; a1.w += xv1.x * wa.w; \
            a2.x += xv2.x * wa.x; a2.y += xv2.x * wa.y; a2.z += xv2.x * wa.z; a2.w += xv2.x * wa.w; \
            a3.x += xv3.x * wa.x; a3.y += xv3.x * wa.y; a3.z += xv3.x * wa.z; a3.w += xv3.x * wa.w; \
            a0.x += xv0.y * wb.x; a0.y += xv0.y * wb.y; a0.z += xv0.y * wb.z; a0.w += xv0.y * wb.w; \
            a1.x += xv1.y * wb.x; a1.y += xv1.y * wb.y; a1.z += xv1.y * wb.z; a1.w += xv1.y * wb.w; \
            a2.x += xv2.y * wb.x; a2.y += xv2.y * wb.y; a2.z += xv2.y * wb.z; a2.w += xv2.y * wb.w; \
            a3.x += xv3.y * wb.x; a3.y += xv3.y * wb.y; a3.z += xv3.y * wb.z; a3.w += xv3.y * wb.w; \
            a0.x += xv0.z * wc.x; a0.y += xv0.z * wc.y; a0.z += xv0.z * wc.z; a0.w += xv0.z * wc.w; \
            a1.x += xv1.z * wc.x; a1.y += xv1.z * wc.y; a1.z += xv1.z * wc.z; a1.w += xv1.z * wc.w; \
            a2.x += xv2.z * wc.x; a2.y += xv2.z * wc.y; a2.z += xv2.z * wc.z; a2.w += xv2.z * wc.w; \
            a3.x += xv3.z * wc.x; a3.y += xv3.z * wc.y; a3.z += xv3.z * wc.z; a3.w += xv3.z * wc.w; \
            a0.x += xv0.w * wd.x; a0.y += xv0.w * wd.y; a0.z += xv0.w * wd.z; a0.w += xv0.w * wd.w; \
            a1.x += xv1.w * wd.x; a1.y += xv1.w * wd.y; a1.z += xv1.w * wd.z; a1.w += xv1.w * wd.w; \
            a2.x += xv2.w * wd.x; a2.y += xv2.w * wd.y; a2.z += xv2.w * wd.z; a2.w += xv2.w * wd.w; \
            a3.x += xv3.w * wd.x; a3.y += xv3.w * wd.y; a3.z += xv3.w * wd.z; a3.w += xv3.w * wd.w;

#define GEMM_PHASE_COMPUTE                                                    \
    {                                                                         \
        const float* x0 = &xs[(r0 + 0) * KP3];                                \
        const float* x1 = &xs[(r0 + 1) * KP3];                                \
        const float* x2 = &xs[(r0 + 2) * KP3];                                \
        const float* x3 = &xs[(r0 + 3) * KP3];                                \
        const float* Wp0 = &Ws[c0];                                           \
        _Pragma("unroll 4")                                                   \
        for (int k4 = 0; k4 < 16; ++k4) {                                     \
            GEMM_K4_BODY                                                      \
        }                                                                     \
    }

// T16[n,NH] (int16) = quant_rowwise( dis[n] * (X[n,128] @ W[128,NH]) );
// rs[n] = rowmax/32767. 64 rows/block, 4x4 per thread. Two 64-wide K phases;
// phase-1 X+W PREFETCHED into 32 VGPRs before phase-0 compute so the phase
// boundary exposes no global latency. KP3=68: 16B-aligned pitch (mandatory
// for b128), 4-row group offset = 16 banks => 2-way alias (free on gfx950).
#define KP3 68
__global__ void __launch_bounds__(256, 4) k_gemm128(
        const float* __restrict__ X, const float* __restrict__ W,
        const float* __restrict__ dis, short* __restrict__ T16,
        float* __restrict__ rs, int n) {
    __shared__ float xs[64 * KP3];     // 17408 B
    __shared__ float Ws[64 * NH];      // 16384 B (one K-half of W)
    __shared__ int rmax[64];
    if (threadIdx.x < 64) rmax[threadIdx.x] = 0;
    long long rowbase = (long long)blockIdx.x * 64;
    int tid = threadIdx.x;
    int c0 = (tid & 15) * 4;
    int r0 = (tid >> 4) * 4;
    const float4* W4 = (const float4*)W;
    // ---- stage phase 0 (load -> LDS)
    #pragma unroll
    for (int u = 0; u < 4; ++u) {
        int i = tid + u * 256;
        int r = i >> 4, kk = (i & 15) << 2;
        float4 xv = (rowbase + r < n)
                        ? *(const float4*)(X + (rowbase + r) * NF + kk)
                        : make_float4(0.f, 0.f, 0.f, 0.f);
        *(float4*)&xs[r * KP3 + kk] = xv;
        ((float4*)Ws)[i] = W4[i];
    }
    // ---- prefetch phase 1 into registers (latency hides under phase 0)
    float4 x1r[4], w1r[4];
    #pragma unroll
    for (int u = 0; u < 4; ++u) {
        int i = tid + u * 256;
        int r = i >> 4, kk = (i & 15) << 2;
        x1r[u] = (rowbase + r < n)
                     ? *(const float4*)(X + (rowbase + r) * NF + 64 + kk)
                     : make_float4(0.f, 0.f, 0.f, 0.f);
        w1r[u] = W4[1024 + i];
    }
    float4 a0{0,0,0,0}, a1{0,0,0,0}, a2{0,0,0,0}, a3{0,0,0,0};
    __syncthreads();
    GEMM_PHASE_COMPUTE
    __syncthreads();
    #pragma unroll
    for (int u = 0; u < 4; ++u) {
        int i = tid + u * 256;
        int r = i >> 4, kk = (i & 15) << 2;
        *(float4*)&xs[r * KP3 + kk] = x1r[u];
        ((float4*)Ws)[i] = w1r[u];
    }
    __syncthreads();
    GEMM_PHASE_COMPUTE
    int row = (int)rowbase + r0;
    float d0 = (row + 0 < n) ? dis[row + 0] : 0.0f;
    float d1 = (row + 1 < n) ? dis[row + 1] : 0.0f;
    float d2 = (row + 2 < n) ? dis[row + 2] : 0.0f;
    float d3 = (row + 3 < n) ? dis[row + 3] : 0.0f;
    a0.x *= d0; a0.y *= d0; a0.z *= d0; a0.w *= d0;
    a1.x *= d1; a1.y *= d1; a1.z *= d1; a1.w *= d1;
    a2.x *= d2; a2.y *= d2; a2.z *= d2; a2.w *= d2;
    a3.x *= d3; a3.y *= d3; a3.z *= d3; a3.w *= d3;
    float m0 = fmaxf(fmaxf(fabsf(a0.x), fabsf(a0.y)), fmaxf(fabsf(a0.z), fabsf(a0.w)));
    float m1 = fmaxf(fmaxf(fabsf(a1.x), fabsf(a1.y)), fmaxf(fabsf(a1.z), fabsf(a1.w)));
    float m2 = fmaxf(fmaxf(fabsf(a2.x), fabsf(a2.y)), fmaxf(fabsf(a2.z), fabsf(a2.w)));
    float m3 = fmaxf(fmaxf(fabsf(a3.x), fabsf(a3.y)), fmaxf(fabsf(a3.z), fabsf(a3.w)));
    atomicMax(&rmax[r0 + 0], __float_as_int(m0));
    atomicMax(&rmax[r0 + 1], __float_as_int(m1));
    atomicMax(&rmax[r0 + 2], __float_as_int(m2));
    atomicMax(&rmax[r0 + 3], __float_as_int(m3));
    __syncthreads();
    float M0 = __int_as_float(rmax[r0 + 0]);
    float M1 = __int_as_float(rmax[r0 + 1]);
    float M2 = __int_as_float(rmax[r0 + 2]);
    float M3 = __int_as_float(rmax[r0 + 3]);
    float i0 = 32767.0f / fmaxf(M0, 1e-20f);
    float i1 = 32767.0f / fmaxf(M1, 1e-20f);
    float i2 = 32767.0f / fmaxf(M2, 1e-20f);
    float i3 = 32767.0f / fmaxf(M3, 1e-20f);
    const float ks = 1.0f / 32767.0f;
    if (row + 0 < n) {
        short4 q = { (short)__float2int_rn(a0.x * i0), (short)__float2int_rn(a0.y * i0),
                     (short)__float2int_rn(a0.z * i0), (short)__float2int_rn(a0.w * i0) };
        *(short4*)&T16[(long long)(row + 0) * NH + c0] = q;
        if (c0 == 0) rs[row + 0] = M0 * ks;
    }
    if (row + 1 < n) {
        short4 q = { (short)__float2int_rn(a1.x * i1), (short)__float2int_rn(a1.y * i1),
                     (short)__float2int_rn(a1.z * i1), (short)__float2int_rn(a1.w * i1) };
        *(short4*)&T16[(long long)(row + 1) * NH + c0] = q;
        if (c0 == 0) rs[row + 1] = M1 * ks;
    }
    if (row + 2 < n) {
        short4 q = { (short)__float2int_rn(a2.x * i2), (short)__float2int_rn(a2.y * i2),
                     (short)__float2int_rn(a2.z * i2), (short)__float2int_rn(a2.w * i2) };
        *(short4*)&T16[(long long)(row + 2) * NH + c0] = q;
        if (c0 == 0) rs[row + 2] = M2 * ks;
    }
    if (row + 3 < n) {
        short4 q = { (short)__float2int_rn(a3.x * i3), (short)__float2int_rn(a3.y * i3),
                     (short)__float2int_rn(a3.z * i3), (short)__float2int_rn(a3.w * i3) };
        *(short4*)&T16[(long long)(row + 3) * NH + c0] = q;
        if (c0 == 0) rs[row + 3] = M3 * ks;
    }
}

// One A-edge / B-edge step: readlane word+scale bits, saddr int16 load, fma.
#define EDGE_A(J) {                                                           \
    int s_ = __builtin_amdgcn_readlane(sA, (J));                              \
    float f_ = __int_as_float(__builtin_amdgcn_readlane(fAb, (J)));           \
    accA = fmaf(f_, (float)(T + s_ * NH)[lane], accA); }
#define EDGE_B(J) {                                                           \
    int s_ = __builtin_amdgcn_readlane(sB, (J));                              \
    float f_ = __int_as_float(__builtin_amdgcn_readlane(fBb, (J)));           \
    accB = fmaf(f_, (float)(T + s_ * NH)[lane], accB); }

// Batch loop over both nodes' edges (expects na/nb_/hasB/lane/ga/gb/sta/stb/
// accA/accB already declared).
#define GATHER_CORE                                                           \
    int gmax = ga > gb ? ga : gb;                                             \
    for (int base = 0; base < gmax; base += 64) {                             \
        int ma = ga - base; ma = ma < 0 ? 0 : (ma > 64 ? 64 : ma);            \
        int mb = gb - base; mb = mb < 0 ? 0 : (mb > 64 ? 64 : mb);            \
        int sA = 0, sB = 0; float fA = 0.0f, fB = 0.0f;                       \
        if (lane < ma) { sA = esrc[sta + base + lane]; fA = rs[sA]; }         \
        if (lane < mb) { sB = esrc[stb + base + lane]; fB = rs[sB]; }         \
        int fAb = __float_as_int(fA), fBb = __float_as_int(fB);               \
        int mmin = ma < mb ? ma : mb;                                         \
        int j = 0;                                                            \
        for (; j + 3 < mmin; j += 4) {                                        \
            EDGE_A(j + 0) EDGE_B(j + 0)                                       \
            EDGE_A(j + 1) EDGE_B(j + 1)                                       \
            EDGE_A(j + 2) EDGE_B(j + 2)                                       \
            EDGE_A(j + 3) EDGE_B(j + 3)                                       \
        }                                                                     \
        int jA = j, jB = j;                                                   \
        for (; jA + 3 < ma; jA += 4) {                                        \
            EDGE_A(jA + 0) EDGE_A(jA + 1) EDGE_A(jA + 2) EDGE_A(jA + 3)       \
        }                                                                     \
        for (; jA < ma; ++jA) EDGE_A(jA)                                      \
        for (; jB + 3 < mb; jB += 4) {                                        \
            EDGE_B(jB + 0) EDGE_B(jB + 1) EDGE_B(jB + 2) EDGE_B(jB + 3)       \
        }                                                                     \
        for (; jB < mb; ++jB) EDGE_B(jB)                                      \
    }

// Full-wave gather prologue + core for the non-persistent kernels.
#define SEG_GATHER2                                                           \
    int lane = threadIdx.x & 63;                                              \
    int na = blockIdx.x * 8 + (threadIdx.x >> 6) * 2;                         \
    int nb_ = na + 1;                                                         \
    if (na >= n) return;                                                      \
    bool hasB = (nb_ < n);                                                    \
    float dia = dis[na];                                                      \
    float dib = hasB ? dis[nb_] : 0.0f;                                       \
    int ga = cnt[na], sta = start[na];                                        \
    int gb = hasB ? cnt[nb_] : 0;                                             \
    int stb = hasB ? start[nb_] : 0;                                          \
    float accA = rs[na] * (float)T[na * NH + lane];                           \
    float accB = hasB ? rs[nb_] * (float)T[nb_ * NH + lane] : 0.0f;           \
    GATHER_CORE

// Layer-0 gather + FUSED layer-1 transform/quant, PERSISTENT blocks:
// W1 staged to LDS once, then grid-stride over node pairs (no barriers in
// the loop; waves iterate independently). h0[lane] = dia*acc + b0[lane];
// o[lane] = sum_c h0[c]*W1[c][lane] via readlane broadcast vs conflict-free
// stride-1 LDS reads; dis-scale + rowwise int16 quant in-wave.
__global__ void __launch_bounds__(256) k_seg0t(
        const short* __restrict__ T, const float* __restrict__ rs,
        const int* __restrict__ esrc, const int* __restrict__ start,
        const int* __restrict__ cnt, const float* __restrict__ dis,
        const float* __restrict__ b0, const float* __restrict__ W1,
        short* __restrict__ To, float* __restrict__ rso, int n) {
    __shared__ float W1s[NH * NH];
    for (int i = threadIdx.x; i < NH * NH / 4; i += 256)
        ((float4*)W1s)[i] = ((const float4*)W1)[i];
    __syncthreads();
    int lane = threadIdx.x & 63;
    int wid = threadIdx.x >> 6;
    float bv = b0[lane];
    const float ks = 1.0f / 32767.0f;
    for (int na = blockIdx.x * 8 + wid * 2; na < n; na += gridDim.x * 8) {
        int nb_ = na + 1;
        bool hasB = (nb_ < n);
        float dia = dis[na];
        float dib = hasB ? dis[nb_] : 0.0f;
        int ga = cnt[na], sta = start[na];
        int gb = hasB ? cnt[nb_] : 0;
        int stb = hasB ? start[nb_] : 0;
        float accA = rs[na] * (float)T[(long long)na * NH + lane];
        float accB = hasB ? rs[nb_] * (float)T[(long long)nb_ * NH + lane] : 0.0f;
        GATHER_CORE
        float hA = dia * accA + bv;
        float hB = dib * accB + bv;      // dib==0 when !hasB (result unused)
        float oA = 0.0f, oB = 0.0f;
        #pragma unroll
        for (int c = 0; c < 64; ++c) {
            float wv = W1s[c * NH + lane];
            float ha = __int_as_float(__builtin_amdgcn_readlane(__float_as_int(hA), c));
            float hb = __int_as_float(__builtin_amdgcn_readlane(__float_as_int(hB), c));
            oA = fmaf(ha, wv, oA);
            oB = fmaf(hb, wv, oB);
        }
        oA *= dia;
        oB *= dib;
        float mA = fabsf(oA), mB = fabsf(oB);
        #pragma unroll
        for (int msk = 32; msk; msk >>= 1) {
            mA = fmaxf(mA, __shfl_xor(mA, msk, 64));
            mB = fmaxf(mB, __shfl_xor(mB, msk, 64));
        }
        float iA = 32767.0f / fmaxf(mA, 1e-20f);
        float iB = 32767.0f / fmaxf(mB, 1e-20f);
        To[(long long)na * NH + lane] = (short)__float2int_rn(oA * iA);
        if (lane == 0) rso[na] = mA * ks;
        if (hasB) {
            To[(long long)nb_ * NH + lane] = (short)__float2int_rn(oB * iB);
            if (lane == 0) rso[nb_] = mB * ks;
        }
    }
}

// Layer-1 + fused layer-2 transform for both nodes: z1[c]=di*acc+b1[c];
// t=tanh(z1); t2 = di*(t @ W2) via 6-step full-wave butterfly (per node).
__global__ void __launch_bounds__(256) k_seg1f(
        const short* __restrict__ T, const float* __restrict__ rs,
        const int* __restrict__ esrc, const int* __restrict__ start,
        const int* __restrict__ cnt, const float* __restrict__ dis,
        const float* __restrict__ b1, const float* __restrict__ W2,
        float2* __restrict__ t2, int n) {
    SEG_GATHER2
    float bv = b1[lane];
    float2 w = ((const float2*)W2)[lane];   // W2[lane][0], W2[lane][1]
    float tA = tanhf(dia * accA + bv);
    float p0 = tA * w.x, p1 = tA * w.y;
    float tB = hasB ? tanhf(dib * accB + bv) : 0.0f;
    float q0 = tB * w.x, q1 = tB * w.y;
    #pragma unroll
    for (int msk = 32; msk; msk >>= 1) {
        p0 += __shfl_xor(p0, msk, 64);
        p1 += __shfl_xor(p1, msk, 64);
        q0 += __shfl_xor(q0, msk, 64);
        q1 += __shfl_xor(q1, msk, 64);
    }
    if (lane == 0) {
        t2[na] = make_float2(dia * p0, dia * p1);
        if (hasB) t2[nb_] = make_float2(dib * q0, dib * q1);
    }
}

// Fused layer-2 aggregation + head, 16 LANES PER NODE (4 nodes/wave):
// lane-parallel edge loads (depth ~1 instead of ~16 serial per thread),
// 4-step shfl_xor reduce within the 16-lane group, then lanes 0-3 of the
// group each write 4 of the 16 output channels (256B contiguous per wave).
__global__ void __launch_bounds__(256) k_seg2f(
        const float2* __restrict__ T2, const int* __restrict__ esrc,
        const int* __restrict__ start, const int* __restrict__ cnt,
        const float* __restrict__ dis, const float* __restrict__ b2,
        const float* __restrict__ Wc, const float* __restrict__ bc,
        float* __restrict__ out, float* __restrict__ emb, int n) {
    int lane = threadIdx.x & 63;
    int sub = lane >> 4;           // node slot within the wave
    int sl = lane & 15;            // lane within the node's 16-lane group
    int i = blockIdx.x * 16 + (threadIdx.x >> 6) * 4 + sub;
    if (i >= n) return;            // whole 16-lane group exits together
    float di = dis[i];
    int g = cnt[i], st = start[i];
    float a0 = 0.0f, a1 = 0.0f;
    for (int j = sl; j < g; j += 16) {
        float2 v = T2[esrc[st + j]];
        a0 += v.x; a1 += v.y;
    }
    if (sl == 0) {
        float2 s = T2[i];
        a0 += s.x; a1 += s.y;
    }
    #pragma unroll
    for (int msk = 8; msk; msk >>= 1) {
        a0 += __shfl_xor(a0, msk, 64);
        a1 += __shfl_xor(a1, msk, 64);
    }
    float e0 = tanhf(a0 * di + b2[0]);
    float e1 = tanhf(a1 * di + b2[1]);
    if (sl == 0) *(float2*)&emb[(long long)i * 2] = make_float2(e0, e1);
    if (sl < 4) {
        int c = sl * 4;
        float4 o;
        o.x = e0 * Wc[c + 0] + e1 * Wc[16 + c + 0] + bc[c + 0];
        o.y = e0 * Wc[c + 1] + e1 * Wc[16 + c + 1] + bc[c + 1];
        o.z = e0 * Wc[c + 2] + e1 * Wc[16 + c + 2] + bc[c + 2];
        o.w = e0 * Wc[c + 3] + e1 * Wc[16 + c + 3] + bc[c + 3];
        *(float4*)&out[(long long)i * 16 + c] = o;
    }
}

extern "C" void kernel_launch(void* const* d_in, const int* in_sizes, int n_in,
                              void* d_out, int out_size, void* d_ws, size_t ws_size,
                              hipStream_t stream) {
    const float* x  = (const float*)d_in[0];
    const int*   ei = (const int*)  d_in[1];
    const float* W0 = (const float*)d_in[2];
    const float* b0 = (const float*)d_in[3];
    const float* W1 = (const float*)d_in[4];
    const float* b1 = (const float*)d_in[5];
    const float* W2 = (const float*)d_in[6];
    const float* b2 = (const float*)d_in[7];
    const float* Wc = (const float*)d_in[8];
    const float* bc = (const float*)d_in[9];

    int N = in_sizes[0] / NF;
    int E = in_sizes[1] / 2;
    int NB = (N + NPB - 1) / NPB;   // 391 for N=100000 (must be <= MAXNB)

    float* out = (float*)d_out;                    // [N,16]
    float* emb = out + (long long)N * 16;          // [N,2]

    // workspace: T16a[N*64 int16 = 12.8MB] | region2[N*64 fp32 = 25.6MB] |
    //            dis[N] | rs_a[N] | cnt[N] | start[N] | esrc[E] | fmt
    // region2 holds the layer-1 quant row T16b (12.8MB) + t2 (0.8MB) + rs_b
    // (0.4MB) -- T16a must stay live while k_seg0t gathers from it.
    // Preprocessing scratch (pairs/blockbase/ccnt/cstart ~ 8MB) overlays T16a
    // (dead until the first k_gemm128).
    short*  T16a = (short*)d_ws;
    char*   r2   = (char*)d_ws + (long long)N * NH * 2;
    short*  T16b = (short*)r2;
    float2* t2   = (float2*)(r2 + (long long)N * NH * 2);
    float*  rs_b = (float*)(r2 + (long long)N * NH * 2 + (long long)N * 8);
    float*  dis  = (float*)((char*)d_ws + (long long)N * NH * 2 + (long long)N * NH * 4);
    float*  rs_a = dis + N;
    int*    cnt   = (int*)(rs_a + N);
    int*    start = cnt + N;
    int*    esrc  = start + N;
    int*    fmt   = esrc + E;

    int* pairs     = (int*)d_ws;                       // E ints (overlay T16a)
    int* blockbase = pairs + E;                        // A1G * NB
    int* ccnt      = blockbase + (long long)A1G * NB;  // NB*16 (line-padded)
    int* cstart    = ccnt + NB * 16;                   // NB

    int nb_g  = (N + 63) / 64;
    int nb_s2 = (N + 7) / 8;
    int nb_2f = (N + 15) / 16;
    int nb_i0 = (NB * 16 + 255) / 256;
    int g_seg0 = 2048;                 // persistent: 8 blocks/CU by LDS+waves
    if (g_seg0 > nb_s2) g_seg0 = nb_s2;

    // per-call two-level bucket sort (inputs restored before every call)
    k_init0   <<<nb_i0, 256, 0, stream>>>(ei, fmt, ccnt, NB * 16);
    k_coarse  <<<A1G, 256, 0, stream>>>(ei, fmt, ccnt, blockbase, E, NB);
    k_cscan   <<<1, 512, 0, stream>>>(ccnt, cstart, NB);
    k_cscatter<<<A1G, 256, 0, stream>>>(ei, fmt, cstart, blockbase, pairs, E, NB);
    k_bucket  <<<NB, 256, 0, stream>>>(pairs, ccnt, cstart, esrc, cnt, start, dis, N);

    // layer 0: fused gemm + rowwise int16 quant
    k_gemm128 <<<nb_g, 256, 0, stream>>>(x, W0, dis, T16a, rs_a, N);

    // layer-0 gather + fused layer-1 transform/quant (persistent blocks)
    k_seg0t   <<<g_seg0, 256, 0, stream>>>(T16a, rs_a, esrc, start, cnt, dis, b0,
                                           W1, T16b, rs_b, N);

    // layer 1 gather + fused layer-2 transform (tanh + @W2 in epilogue)
    k_seg1f   <<<nb_s2, 256, 0, stream>>>(T16b, rs_b, esrc, start, cnt, dis, b1,
                                          W2, t2, N);

    // layer-2 aggregation + head (16 lanes per node)
    k_seg2f   <<<nb_2f, 256, 0, stream>>>(t2, esrc, start, cnt, dis, b2, Wc, bc,
                                          out, emb, N);
}

// Round 4
// 353.104 us; speedup vs baseline: 1.0200x; 1.0200x over previous
//
#include <hip/hip_runtime.h>

// GCN forward: 3x GCNConv (128->64->64->2) + linear head (2->16).
// N=100000 nodes, E=1600000 edges (+self-loops handled analytically).
// Preprocessing: two-level LDS bucket sort. Aggregation: atomic-free
// FULL-WAVE segment-sum gathers (lane = channel); TWO nodes per wave.
// Round 20:
//  - REVERTED round-19 regressions: persistent seg0t (VGPR 24->64, occ
//    72->36%, 74.5->91.9us -- fixed-assignment lost dynamic load balancing
//    over skewed per-block work) and gemm128 reg-prefetch (unverified, part
//    of the residual +10us). Both back to round-18 forms.
//  - Layer-1 rows now PRE-SCALED FP32 (T32b): seg0t writes o=dia*(h0@W1)
//    directly (quant epilogue deleted); seg1f edge step drops the scale
//    readlane + cvt + rs[] random gather: 5-6 VALU issues/edge -> 3.
//    T32b (25.6MB) is L3-resident; t2 overlays dead T16a so the workspace
//    footprint does not grow.
//  - k_seg2f kept at 16-lanes-per-node (round-19 form).
// BANNED (measured failures): half-wave/2-rows-per-load gather (~3e-3 absmax,
// rounds 7-9/11); SGPR-indexed rs[] (s_load thrash, r13); LDS float atomicAdd
// (CAS storm, r15); LDS row pitch not 0 mod 16B in float4 tiles (r17);
// 64-entry per-lane VGPR arrays in gather kernels (occupancy halved, r17);
// persistent grid-stride gather blocks (load imbalance + VGPR, r19).
// dis[] pre-folded: T'[v]=dis[v]*t[v] => O[i]=dis[i]*(T'[i]+sum T'[s])+b.

#define NF 128
#define NH 64
#define NPB 256      // nodes per coarse bucket (bucket = dst >> 8)
#define MAXNB 512    // max coarse buckets (N < 131072, matches 17-bit src pack)
#define CAP 6144     // max edges per coarse bucket (mean 4096, >30 sigma)
#define A1G 1024     // grid for coarse count/scatter (must match between them)

// Zero coarse counters + detect int64 vs int32 edge_index layout.
__global__ void k_init0(const int* __restrict__ ei, int* __restrict__ fmt,
                        int* __restrict__ ccnt, int nb16) {
    int i = blockIdx.x * 256 + threadIdx.x;
    if (i < nb16) ccnt[i] = 0;
    if (i == 0) {
        int f = 1;
        #pragma unroll
        for (int k = 1; k < 32; k += 2) if (ei[k] != 0) f = 0;
        *fmt = f;   // 1 => int64 (stride 2 in int32 words), 0 => int32
    }
}

// Coarse count: LDS histogram per block, then reserve per-(block,bucket) space
// with ONE padded global atomic per bucket per block (line-parallel).
__global__ void __launch_bounds__(256) k_coarse(
        const int* __restrict__ ei, const int* __restrict__ fmt,
        int* __restrict__ ccnt, int* __restrict__ blockbase, int E, int NB) {
    __shared__ int h[MAXNB];
    int sh = *fmt;
    for (int i = threadIdx.x; i < NB; i += 256) h[i] = 0;
    __syncthreads();
    for (long long e = (long long)blockIdx.x * 256 + threadIdx.x; e < E;
         e += (long long)A1G * 256) {
        int d = ei[(long long)(E + e) << sh];
        atomicAdd(&h[d >> 8], 1);
    }
    __syncthreads();
    for (int b = threadIdx.x; b < NB; b += 256) {
        int c = h[b];
        int base = (c > 0) ? atomicAdd(&ccnt[b * 16], c) : 0;
        blockbase[(long long)blockIdx.x * NB + b] = base;
    }
}

// Exclusive scan of the NB coarse counts (single block).
__global__ void __launch_bounds__(512) k_cscan(
        const int* __restrict__ ccnt, int* __restrict__ cstart, int NB) {
    __shared__ int s[512];
    int t = threadIdx.x;
    int c = (t < NB) ? ccnt[t * 16] : 0;
    s[t] = c;
    __syncthreads();
    for (int off = 1; off < 512; off <<= 1) {
        int v = s[t];
        int u = (t >= off) ? s[t - off] : 0;
        __syncthreads();
        s[t] = v + u;
        __syncthreads();
    }
    if (t < NB) cstart[t] = s[t] - c;
}

// Coarse scatter: same grid-stride partition as k_coarse, so this block's
// per-bucket totals equal its reservation. Edge packed as src|(dst&255)<<17.
__global__ void __launch_bounds__(256) k_cscatter(
        const int* __restrict__ ei, const int* __restrict__ fmt,
        const int* __restrict__ cstart, const int* __restrict__ blockbase,
        int* __restrict__ pairs, int E, int NB) {
    __shared__ int h[MAXNB];
    __shared__ int bb[MAXNB];
    int sh = *fmt;
    for (int i = threadIdx.x; i < NB; i += 256) {
        h[i] = 0;
        bb[i] = cstart[i] + blockbase[(long long)blockIdx.x * NB + i];
    }
    __syncthreads();
    for (long long e = (long long)blockIdx.x * 256 + threadIdx.x; e < E;
         e += (long long)A1G * 256) {
        int s = ei[(long long)e << sh];
        int d = ei[(long long)(E + e) << sh];
        int b = d >> 8;
        int r = atomicAdd(&h[b], 1);
        pairs[bb[b] + r] = s | ((d & 255) << 17);
    }
}

// Fine sort: one block per coarse bucket, entirely in LDS. Emits cnt/start/dis
// (coalesced) and esrc (scatter within the bucket's contiguous window).
__global__ void __launch_bounds__(256) k_bucket(
        const int* __restrict__ pairs, const int* __restrict__ ccnt,
        const int* __restrict__ cstart, int* __restrict__ esrc,
        int* __restrict__ cnt, int* __restrict__ start, float* __restrict__ dis,
        int N) {
    __shared__ int words[CAP];
    __shared__ unsigned char rk[CAP];
    __shared__ int h[NPB];
    __shared__ int hs[NPB];
    int b = blockIdx.x;
    int cs = cstart[b];
    int ec = ccnt[b * 16];
    if (ec > CAP) ec = CAP;          // memory-safety clamp (P ~ 0 for uniform dst)
    int t = threadIdx.x;
    for (int i = t; i < ec; i += 256) words[i] = pairs[cs + i];
    h[t] = 0;
    __syncthreads();
    for (int i = t; i < ec; i += 256) {
        int ld = words[i] >> 17;
        rk[i] = (unsigned char)atomicAdd(&h[ld], 1);
    }
    __syncthreads();
    int c = h[t];
    hs[t] = c;
    __syncthreads();
    for (int off = 1; off < 256; off <<= 1) {
        int v = hs[t];
        int u = (t >= off) ? hs[t - off] : 0;
        __syncthreads();
        hs[t] = v + u;               // inclusive scan
        __syncthreads();
    }
    int node = b * NPB + t;
    if (node < N) {
        cnt[node] = c;
        start[node] = cs + hs[t] - c;
        dis[node] = rsqrtf(1.0f + (float)c);   // degree includes self-loop
    }
    for (int i = t; i < ec; i += 256) {
        int w = words[i];
        int ld = w >> 17;
        esrc[cs + (hs[ld] - h[ld]) + rk[i]] = w & 0x1FFFF;
    }
}

// T16[n,NH] (int16) = quant_rowwise( dis[n] * (X[n,128] @ W[128,NH]) );
// rs[n] = rowmax/32767. 64 rows/block, 4x4 per thread; K split into two
// 64-wide phases with BOTH xs half AND Ws half (16KB) staged per phase:
// LDS ~34KB => 3 blocks/CU. KP3=68: pitch 272B (16B-aligned, mandatory for
// b128) and 4-row group offset = 16 banks => 2-way alias (free on gfx950).
#define KP3 68
__global__ void __launch_bounds__(256) k_gemm128(
        const float* __restrict__ X, const float* __restrict__ W,
        const float* __restrict__ dis, short* __restrict__ T16,
        float* __restrict__ rs, int n) {
    __shared__ float xs[64 * KP3];     // 17408 B
    __shared__ float Ws[64 * NH];      // 16384 B (one K-half of W)
    __shared__ int rmax[64];
    if (threadIdx.x < 64) rmax[threadIdx.x] = 0;
    long long rowbase = (long long)blockIdx.x * 64;
    int c0 = (threadIdx.x & 15) * 4;
    int r0 = (threadIdx.x >> 4) * 4;
    float4 a0{0,0,0,0}, a1{0,0,0,0}, a2{0,0,0,0}, a3{0,0,0,0};
    #pragma unroll
    for (int ph = 0; ph < 2; ++ph) {
        if (ph) __syncthreads();     // phase-0 compute done before overwrite
        // stage this K-half of W (rows ph*64..ph*64+63, contiguous 16KB)
        const float4* Wp4 = (const float4*)(W + (long long)ph * 64 * NH);
        for (int i = threadIdx.x; i < 64 * NH / 4; i += 256)
            ((float4*)Ws)[i] = Wp4[i];
        // stage this K-half of X rows
        const float* Xp = X + rowbase * NF + ph * 64;
        for (int i = threadIdx.x; i < 1024; i += 256) {
            int r = i >> 4, kk = (i & 15) << 2;
            float4 v = (rowbase + r < n)
                           ? *(const float4*)(Xp + r * NF + kk)
                           : make_float4(0.f, 0.f, 0.f, 0.f);
            *(float4*)&xs[r * KP3 + kk] = v;
        }
        __syncthreads();
        const float* x0 = &xs[(r0 + 0) * KP3];
        const float* x1 = &xs[(r0 + 1) * KP3];
        const float* x2 = &xs[(r0 + 2) * KP3];
        const float* x3 = &xs[(r0 + 3) * KP3];
        const float* Wp0 = &Ws[c0];
        #pragma unroll 4
        for (int k4 = 0; k4 < 16; ++k4) {
            float4 xv0 = *(const float4*)(x0 + k4 * 4);
            float4 xv1 = *(const float4*)(x1 + k4 * 4);
            float4 xv2 = *(const float4*)(x2 + k4 * 4);
            float4 xv3 = *(const float4*)(x3 + k4 * 4);
            float4 wa = *(const float4*)(Wp0 + (k4 * 4 + 0) * NH);
            float4 wb = *(const float4*)(Wp0 + (k4 * 4 + 1) * NH);
            float4 wc = *(const float4*)(Wp0 + (k4 * 4 + 2) * NH);
            float4 wd = *(const float4*)(Wp0 + (k4 * 4 + 3) * NH);
            // k4*4+0
            a0.x += xv0.x * wa.x; a0.y += xv0.x * wa.y; a0.z += xv0.x * wa.z; a0.w += xv0.x * wa.w;
            a1.x += xv1.x * wa.x; a1.y += xv1.x * wa.y; a1.z += xv1.x * wa.z; a1.w += xv1.x * wa.w;
            a2.x += xv2.x * wa.x; a2.y += xv2.x * wa.y; a2.z += xv2.x * wa.z; a2.w += xv2.x * wa.w;
            a3.x += xv3.x * wa.x; a3.y += xv3.x * wa.y; a3.z += xv3.x * wa.z; a3.w += xv3.x * wa.w;
            // k4*4+1
            a0.x += xv0.y * wb.x; a0.y += xv0.y * wb.y; a0.z += xv0.y * wb.z; a0.w += xv0.y * wb.w;
            a1.x += xv1.y * wb.x; a1.y += xv1.y * wb.y; a1.z += xv1.y * wb.z; a1.w += xv1.y * wb.w;
            a2.x += xv2.y * wb.x; a2.y += xv2.y * wb.y; a2.z += xv2.y * wb.z; a2.w += xv2.y * wb.w;
            a3.x += xv3.y * wb.x; a3.y += xv3.y * wb.y; a3.z += xv3.y * wb.z; a3.w += xv3.y * wb.w;
            // k4*4+2
            a0.x += xv0.z * wc.x; a0.y += xv0.z * wc.y; a0.z += xv0.z * wc.z; a0.w += xv0.z * wc.w;
            a1.x += xv1.z * wc.x; a1.y += xv1.z * wc.y; a1.z += xv1.z * wc.z; a1.w += xv1.z * wc.w;
            a2.x += xv2.z * wc.x; a2.y += xv2.z * wc.y; a2.z += xv2.z * wc.z; a2.w += xv2.z * wc.w;
            a3.x += xv3.z * wc.x; a3.y += xv3.z * wc.y; a3.z += xv3.z * wc.z; a3.w += xv3.z * wc.w;
            // k4*4+3
            a0.x += xv0.w * wd.x; a0.y += xv0.w * wd.y; a0.z += xv0.w * wd.z; a0.w += xv0.w * wd.w;
            a1.x += xv1.w * wd.x; a1.y += xv1.w * wd.y; a1.z += xv1.w * wd.z; a1.w += xv1.w * wd.w;
            a2.x += xv2.w * wd.x; a2.y += xv2.w * wd.y; a2.z += xv2.w * wd.z; a2.w += xv2.w * wd.w;
            a3.x += xv3.w * wd.x; a3.y += xv3.w * wd.y; a3.z += xv3.w * wd.z; a3.w += xv3.w * wd.w;
        }
    }
    int row = (int)rowbase + r0;
    float d0 = (row + 0 < n) ? dis[row + 0] : 0.0f;
    float d1 = (row + 1 < n) ? dis[row + 1] : 0.0f;
    float d2 = (row + 2 < n) ? dis[row + 2] : 0.0f;
    float d3 = (row + 3 < n) ? dis[row + 3] : 0.0f;
    a0.x *= d0; a0.y *= d0; a0.z *= d0; a0.w *= d0;
    a1.x *= d1; a1.y *= d1; a1.z *= d1; a1.w *= d1;
    a2.x *= d2; a2.y *= d2; a2.z *= d2; a2.w *= d2;
    a3.x *= d3; a3.y *= d3; a3.z *= d3; a3.w *= d3;
    float m0 = fmaxf(fmaxf(fabsf(a0.x), fabsf(a0.y)), fmaxf(fabsf(a0.z), fabsf(a0.w)));
    float m1 = fmaxf(fmaxf(fabsf(a1.x), fabsf(a1.y)), fmaxf(fabsf(a1.z), fabsf(a1.w)));
    float m2 = fmaxf(fmaxf(fabsf(a2.x), fabsf(a2.y)), fmaxf(fabsf(a2.z), fabsf(a2.w)));
    float m3 = fmaxf(fmaxf(fabsf(a3.x), fabsf(a3.y)), fmaxf(fabsf(a3.z), fabsf(a3.w)));
    atomicMax(&rmax[r0 + 0], __float_as_int(m0));
    atomicMax(&rmax[r0 + 1], __float_as_int(m1));
    atomicMax(&rmax[r0 + 2], __float_as_int(m2));
    atomicMax(&rmax[r0 + 3], __float_as_int(m3));
    __syncthreads();
    float M0 = __int_as_float(rmax[r0 + 0]);
    float M1 = __int_as_float(rmax[r0 + 1]);
    float M2 = __int_as_float(rmax[r0 + 2]);
    float M3 = __int_as_float(rmax[r0 + 3]);
    float i0 = 32767.0f / fmaxf(M0, 1e-20f);
    float i1 = 32767.0f / fmaxf(M1, 1e-20f);
    float i2 = 32767.0f / fmaxf(M2, 1e-20f);
    float i3 = 32767.0f / fmaxf(M3, 1e-20f);
    const float ks = 1.0f / 32767.0f;
    if (row + 0 < n) {
        short4 q = { (short)__float2int_rn(a0.x * i0), (short)__float2int_rn(a0.y * i0),
                     (short)__float2int_rn(a0.z * i0), (short)__float2int_rn(a0.w * i0) };
        *(short4*)&T16[(long long)(row + 0) * NH + c0] = q;
        if (c0 == 0) rs[row + 0] = M0 * ks;
    }
    if (row + 1 < n) {
        short4 q = { (short)__float2int_rn(a1.x * i1), (short)__float2int_rn(a1.y * i1),
                     (short)__float2int_rn(a1.z * i1), (short)__float2int_rn(a1.w * i1) };
        *(short4*)&T16[(long long)(row + 1) * NH + c0] = q;
        if (c0 == 0) rs[row + 1] = M1 * ks;
    }
    if (row + 2 < n) {
        short4 q = { (short)__float2int_rn(a2.x * i2), (short)__float2int_rn(a2.y * i2),
                     (short)__float2int_rn(a2.z * i2), (short)__float2int_rn(a2.w * i2) };
        *(short4*)&T16[(long long)(row + 2) * NH + c0] = q;
        if (c0 == 0) rs[row + 2] = M2 * ks;
    }
    if (row + 3 < n) {
        short4 q = { (short)__float2int_rn(a3.x * i3), (short)__float2int_rn(a3.y * i3),
                     (short)__float2int_rn(a3.z * i3), (short)__float2int_rn(a3.w * i3) };
        *(short4*)&T16[(long long)(row + 3) * NH + c0] = q;
        if (c0 == 0) rs[row + 3] = M3 * ks;
    }
}

// int16-row edge step: readlane word+scale bits, saddr int16 load, cvt, fma.
#define EDGE_A(J) {                                                           \
    int s_ = __builtin_amdgcn_readlane(sA, (J));                              \
    float f_ = __int_as_float(__builtin_amdgcn_readlane(fAb, (J)));           \
    accA = fmaf(f_, (float)(T + s_ * NH)[lane], accA); }
#define EDGE_B(J) {                                                           \
    int s_ = __builtin_amdgcn_readlane(sB, (J));                              \
    float f_ = __int_as_float(__builtin_amdgcn_readlane(fBb, (J)));           \
    accB = fmaf(f_, (float)(T + s_ * NH)[lane], accB); }

// fp32 pre-scaled row edge step: readlane word, dword load, add (3 issues).
#define EDGE_A32(J) {                                                         \
    int s_ = __builtin_amdgcn_readlane(sA, (J));                              \
    accA += (Tf + s_ * NH)[lane]; }
#define EDGE_B32(J) {                                                         \
    int s_ = __builtin_amdgcn_readlane(sB, (J));                              \
    accB += (Tf + s_ * NH)[lane]; }

// Full-wave gather over int16 rows + rs scales, TWO nodes per wave (A,B).
#define SEG_GATHER2_I16                                                       \
    int lane = threadIdx.x & 63;                                              \
    int na = blockIdx.x * 8 + (threadIdx.x >> 6) * 2;                         \
    int nb_ = na + 1;                                                         \
    if (na >= n) return;                                                      \
    bool hasB = (nb_ < n);                                                    \
    float dia = dis[na];                                                      \
    float dib = hasB ? dis[nb_] : 0.0f;                                       \
    int ga = cnt[na], sta = start[na];                                        \
    int gb = hasB ? cnt[nb_] : 0;                                             \
    int stb = hasB ? start[nb_] : 0;                                          \
    float accA = rs[na] * (float)T[na * NH + lane];                           \
    float accB = hasB ? rs[nb_] * (float)T[nb_ * NH + lane] : 0.0f;           \
    int gmax = ga > gb ? ga : gb;                                             \
    for (int base = 0; base < gmax; base += 64) {                             \
        int ma = ga - base; ma = ma < 0 ? 0 : (ma > 64 ? 64 : ma);            \
        int mb = gb - base; mb = mb < 0 ? 0 : (mb > 64 ? 64 : mb);            \
        int sA = 0, sB = 0; float fA = 0.0f, fB = 0.0f;                       \
        if (lane < ma) { sA = esrc[sta + base + lane]; fA = rs[sA]; }         \
        if (lane < mb) { sB = esrc[stb + base + lane]; fB = rs[sB]; }         \
        int fAb = __float_as_int(fA), fBb = __float_as_int(fB);               \
        int mmin = ma < mb ? ma : mb;                                         \
        int j = 0;                                                            \
        for (; j + 3 < mmin; j += 4) {                                        \
            EDGE_A(j + 0) EDGE_B(j + 0)                                       \
            EDGE_A(j + 1) EDGE_B(j + 1)                                       \
            EDGE_A(j + 2) EDGE_B(j + 2)                                       \
            EDGE_A(j + 3) EDGE_B(j + 3)                                       \
        }                                                                     \
        int jA = j, jB = j;                                                   \
        for (; jA + 3 < ma; jA += 4) {                                        \
            EDGE_A(jA + 0) EDGE_A(jA + 1) EDGE_A(jA + 2) EDGE_A(jA + 3)       \
        }                                                                     \
        for (; jA < ma; ++jA) EDGE_A(jA)                                      \
        for (; jB + 3 < mb; jB += 4) {                                        \
            EDGE_B(jB + 0) EDGE_B(jB + 1) EDGE_B(jB + 2) EDGE_B(jB + 3)       \
        }                                                                     \
        for (; jB < mb; ++jB) EDGE_B(jB)                                      \
    }

// Full-wave gather over PRE-SCALED fp32 rows (no rs, no cvt, add not fma).
#define SEG_GATHER2_F32                                                       \
    int lane = threadIdx.x & 63;                                              \
    int na = blockIdx.x * 8 + (threadIdx.x >> 6) * 2;                         \
    int nb_ = na + 1;                                                         \
    if (na >= n) return;                                                      \
    bool hasB = (nb_ < n);                                                    \
    float dia = dis[na];                                                      \
    float dib = hasB ? dis[nb_] : 0.0f;                                       \
    int ga = cnt[na], sta = start[na];                                        \
    int gb = hasB ? cnt[nb_] : 0;                                             \
    int stb = hasB ? start[nb_] : 0;                                          \
    float accA = Tf[na * NH + lane];                                          \
    float accB = hasB ? Tf[nb_ * NH + lane] : 0.0f;                           \
    int gmax = ga > gb ? ga : gb;                                             \
    for (int base = 0; base < gmax; base += 64) {                             \
        int ma = ga - base; ma = ma < 0 ? 0 : (ma > 64 ? 64 : ma);            \
        int mb = gb - base; mb = mb < 0 ? 0 : (mb > 64 ? 64 : mb);            \
        int sA = 0, sB = 0;                                                   \
        if (lane < ma) sA = esrc[sta + base + lane];                          \
        if (lane < mb) sB = esrc[stb + base + lane];                          \
        int mmin = ma < mb ? ma : mb;                                         \
        int j = 0;                                                            \
        for (; j + 3 < mmin; j += 4) {                                        \
            EDGE_A32(j + 0) EDGE_B32(j + 0)                                   \
            EDGE_A32(j + 1) EDGE_B32(j + 1)                                   \
            EDGE_A32(j + 2) EDGE_B32(j + 2)                                   \
            EDGE_A32(j + 3) EDGE_B32(j + 3)                                   \
        }                                                                     \
        int jA = j, jB = j;                                                   \
        for (; jA + 3 < ma; jA += 4) {                                        \
            EDGE_A32(jA + 0) EDGE_A32(jA + 1) EDGE_A32(jA + 2) EDGE_A32(jA + 3) \
        }                                                                     \
        for (; jA < ma; ++jA) EDGE_A32(jA)                                    \
        for (; jB + 3 < mb; jB += 4) {                                        \
            EDGE_B32(jB + 0) EDGE_B32(jB + 1) EDGE_B32(jB + 2) EDGE_B32(jB + 3) \
        }                                                                     \
        for (; jB < mb; ++jB) EDGE_B32(jB)                                    \
    }

// Layer-0 gather + FUSED layer-1 transform (replaces k_seg + k_gemm<64>):
// h0[lane] = dia*acc + b0[lane] (full row held one channel per lane);
// o[lane] = sum_c h0[c]*W1[c][lane] via readlane broadcast vs conflict-free
// stride-1 LDS W1 reads. Output written as PRE-SCALED fp32 rows
// To[v] = dis[v] * o  (no quant epilogue, no rs_b).
__global__ void __launch_bounds__(256) k_seg0t(
        const short* __restrict__ T, const float* __restrict__ rs,
        const int* __restrict__ esrc, const int* __restrict__ start,
        const int* __restrict__ cnt, const float* __restrict__ dis,
        const float* __restrict__ b0, const float* __restrict__ W1,
        float* __restrict__ To, int n) {
    __shared__ float W1s[NH * NH];
    for (int i = threadIdx.x; i < NH * NH / 4; i += 256)
        ((float4*)W1s)[i] = ((const float4*)W1)[i];
    __syncthreads();      // before any early return (divergent-exit barrier UB)
    SEG_GATHER2_I16
    float bv = b0[lane];
    float hA = dia * accA + bv;
    float hB = dib * accB + bv;      // dib==0 when !hasB (result unused)
    float oA = 0.0f, oB = 0.0f;
    #pragma unroll
    for (int c = 0; c < 64; ++c) {
        float wv = W1s[c * NH + lane];
        float ha = __int_as_float(__builtin_amdgcn_readlane(__float_as_int(hA), c));
        float hb = __int_as_float(__builtin_amdgcn_readlane(__float_as_int(hB), c));
        oA = fmaf(ha, wv, oA);
        oB = fmaf(hb, wv, oB);
    }
    To[(long long)na * NH + lane] = oA * dia;
    if (hasB) To[(long long)nb_ * NH + lane] = oB * dib;
}

// Layer-1 aggregation (fp32 pre-scaled rows) + fused layer-2 transform:
// z1[c]=di*acc+b1[c]; t=tanh(z1); t2 = di*(t @ W2) via full-wave butterfly.
__global__ void __launch_bounds__(256) k_seg1f(
        const float* __restrict__ Tf, const int* __restrict__ esrc,
        const int* __restrict__ start, const int* __restrict__ cnt,
        const float* __restrict__ dis, const float* __restrict__ b1,
        const float* __restrict__ W2, float2* __restrict__ t2, int n) {
    SEG_GATHER2_F32
    float bv = b1[lane];
    float2 w = ((const float2*)W2)[lane];   // W2[lane][0], W2[lane][1]
    float tA = tanhf(dia * accA + bv);
    float p0 = tA * w.x, p1 = tA * w.y;
    float tB = hasB ? tanhf(dib * accB + bv) : 0.0f;
    float q0 = tB * w.x, q1 = tB * w.y;
    #pragma unroll
    for (int msk = 32; msk; msk >>= 1) {
        p0 += __shfl_xor(p0, msk, 64);
        p1 += __shfl_xor(p1, msk, 64);
        q0 += __shfl_xor(q0, msk, 64);
        q1 += __shfl_xor(q1, msk, 64);
    }
    if (lane == 0) {
        t2[na] = make_float2(dia * p0, dia * p1);
        if (hasB) t2[nb_] = make_float2(dib * q0, dib * q1);
    }
}

// Fused layer-2 aggregation + head, 16 LANES PER NODE (4 nodes/wave):
// lane-parallel edge loads (depth ~1 instead of ~16 serial per thread),
// 4-step shfl_xor reduce within the 16-lane group, then lanes 0-3 of the
// group each write 4 of the 16 output channels.
__global__ void __launch_bounds__(256) k_seg2f(
        const float2* __restrict__ T2, const int* __restrict__ esrc,
        const int* __restrict__ start, const int* __restrict__ cnt,
        const float* __restrict__ dis, const float* __restrict__ b2,
        const float* __restrict__ Wc, const float* __restrict__ bc,
        float* __restrict__ out, float* __restrict__ emb, int n) {
    int lane = threadIdx.x & 63;
    int sub = lane >> 4;           // node slot within the wave
    int sl = lane & 15;            // lane within the node's 16-lane group
    int i = blockIdx.x * 16 + (threadIdx.x >> 6) * 4 + sub;
    if (i >= n) return;            // whole 16-lane group exits together
    float di = dis[i];
    int g = cnt[i], st = start[i];
    float a0 = 0.0f, a1 = 0.0f;
    for (int j = sl; j < g; j += 16) {
        float2 v = T2[esrc[st + j]];
        a0 += v.x; a1 += v.y;
    }
    if (sl == 0) {
        float2 s = T2[i];
        a0 += s.x; a1 += s.y;
    }
    #pragma unroll
    for (int msk = 8; msk; msk >>= 1) {
        a0 += __shfl_xor(a0, msk, 64);
        a1 += __shfl_xor(a1, msk, 64);
    }
    float e0 = tanhf(a0 * di + b2[0]);
    float e1 = tanhf(a1 * di + b2[1]);
    if (sl == 0) *(float2*)&emb[(long long)i * 2] = make_float2(e0, e1);
    if (sl < 4) {
        int c = sl * 4;
        float4 o;
        o.x = e0 * Wc[c + 0] + e1 * Wc[16 + c + 0] + bc[c + 0];
        o.y = e0 * Wc[c + 1] + e1 * Wc[16 + c + 1] + bc[c + 1];
        o.z = e0 * Wc[c + 2] + e1 * Wc[16 + c + 2] + bc[c + 2];
        o.w = e0 * Wc[c + 3] + e1 * Wc[16 + c + 3] + bc[c + 3];
        *(float4*)&out[(long long)i * 16 + c] = o;
    }
}

extern "C" void kernel_launch(void* const* d_in, const int* in_sizes, int n_in,
                              void* d_out, int out_size, void* d_ws, size_t ws_size,
                              hipStream_t stream) {
    const float* x  = (const float*)d_in[0];
    const int*   ei = (const int*)  d_in[1];
    const float* W0 = (const float*)d_in[2];
    const float* b0 = (const float*)d_in[3];
    const float* W1 = (const float*)d_in[4];
    const float* b1 = (const float*)d_in[5];
    const float* W2 = (const float*)d_in[6];
    const float* b2 = (const float*)d_in[7];
    const float* Wc = (const float*)d_in[8];
    const float* bc = (const float*)d_in[9];

    int N = in_sizes[0] / NF;
    int E = in_sizes[1] / 2;
    int NB = (N + NPB - 1) / NPB;   // 391 for N=100000 (must be <= MAXNB)

    float* out = (float*)d_out;                    // [N,16]
    float* emb = out + (long long)N * 16;          // [N,2]

    // workspace: T16a[N*64 int16 = 12.8MB] | T32b[N*64 fp32 = 25.6MB] |
    //            dis[N] | rs_a[N] | cnt[N] | start[N] | esrc[E] | fmt
    // t2 (0.8MB) OVERLAYS T16a: T16a is dead once k_seg0t finishes, and
    // t2 is first written by k_seg1f. Preprocessing scratch (~8MB:
    // pairs/blockbase/ccnt/cstart) also overlays T16a (dead until k_gemm128).
    short*  T16a = (short*)d_ws;
    float*  T32b = (float*)((char*)d_ws + (long long)N * NH * 2);
    float*  dis  = (float*)((char*)d_ws + (long long)N * NH * 2 + (long long)N * NH * 4);
    float*  rs_a = dis + N;
    int*    cnt   = (int*)(rs_a + N);
    int*    start = cnt + N;
    int*    esrc  = start + N;
    int*    fmt   = esrc + E;
    float2* t2    = (float2*)d_ws;                     // overlays dead T16a

    int* pairs     = (int*)d_ws;                       // E ints (overlay T16a)
    int* blockbase = pairs + E;                        // A1G * NB
    int* ccnt      = blockbase + (long long)A1G * NB;  // NB*16 (line-padded)
    int* cstart    = ccnt + NB * 16;                   // NB

    int nb_g  = (N + 63) / 64;
    int nb_s2 = (N + 7) / 8;
    int nb_2f = (N + 15) / 16;
    int nb_i0 = (NB * 16 + 255) / 256;

    // per-call two-level bucket sort (inputs restored before every call)
    k_init0   <<<nb_i0, 256, 0, stream>>>(ei, fmt, ccnt, NB * 16);
    k_coarse  <<<A1G, 256, 0, stream>>>(ei, fmt, ccnt, blockbase, E, NB);
    k_cscan   <<<1, 512, 0, stream>>>(ccnt, cstart, NB);
    k_cscatter<<<A1G, 256, 0, stream>>>(ei, fmt, cstart, blockbase, pairs, E, NB);
    k_bucket  <<<NB, 256, 0, stream>>>(pairs, ccnt, cstart, esrc, cnt, start, dis, N);

    // layer 0: fused gemm + rowwise int16 quant
    k_gemm128 <<<nb_g, 256, 0, stream>>>(x, W0, dis, T16a, rs_a, N);

    // layer-0 gather + fused layer-1 transform -> pre-scaled fp32 rows
    k_seg0t   <<<nb_s2, 256, 0, stream>>>(T16a, rs_a, esrc, start, cnt, dis, b0,
                                          W1, T32b, N);

    // layer 1 gather (fp32 rows) + fused layer-2 transform
    k_seg1f   <<<nb_s2, 256, 0, stream>>>(T32b, esrc, start, cnt, dis, b1,
                                          W2, t2, N);

    // layer-2 aggregation + head (16 lanes per node)
    k_seg2f   <<<nb_2f, 256, 0, stream>>>(t2, esrc, start, cnt, dis, b2, Wc, bc,
                                          out, emb, N);
}

// Round 5
// 331.253 us; speedup vs baseline: 1.0873x; 1.0660x over previous
//
#include <hip/hip_runtime.h>

// GCN forward: 3x GCNConv (128->64->64->2) + linear head (2->16).
// N=100000 nodes, E=1600000 edges (+self-loops handled analytically).
// Preprocessing: two-level LDS bucket sort. Aggregation: atomic-free
// FULL-WAVE segment-sum gathers (lane = channel) over int16 rows with
// per-row scales; TWO nodes per wave interleaved.
// Round 21 (consolidation): exact round-18 config (best: 333us) plus
//  - k_seg2f 16-lanes-per-node (old form: 391 blocks = 1.5 waves/SIMD,
//    ~16 serial random 8B loads/thread = latency exposure).
//  - k_seg0t matvec even/odd accumulator split (halves the 64-deep fma
//    dependence chains; zero extra instructions).
// REGIME NOTE (r20 measured): gather kernels are RANDOM-ROW-TRAFFIC bound,
// not VALU bound: seg1f moves ~87GB L2-miss traffic (L3-resident rows) at
// ~1.85 TB/s effective. int16 rows ARE the bandwidth optimization: fp32
// rows (256B/edge) regressed seg1f ~+20us despite a 3-op edge step.
// BANNED (measured failures): half-wave/2-rows-per-load gather (~3e-3 absmax,
// rounds 7-9/11); SGPR-indexed rs[] (s_load thrash, r13); LDS float atomicAdd
// (CAS storm, r15); LDS row pitch not 0 mod 16B in float4 tiles (r17);
// 64-entry per-lane VGPR arrays in gather kernels (occupancy halved, r17);
// persistent grid-stride gather blocks (load imbalance + VGPR, r19);
// fp32 pre-scaled gather rows (2x traffic on traffic-bound gather, r20).
// dis[] pre-folded: T'[v]=dis[v]*t[v] => O[i]=dis[i]*(T'[i]+sum T'[s])+b.

#define NF 128
#define NH 64
#define NPB 256      // nodes per coarse bucket (bucket = dst >> 8)
#define MAXNB 512    // max coarse buckets (N < 131072, matches 17-bit src pack)
#define CAP 6144     // max edges per coarse bucket (mean 4096, >30 sigma)
#define A1G 1024     // grid for coarse count/scatter (must match between them)

// Zero coarse counters + detect int64 vs int32 edge_index layout.
__global__ void k_init0(const int* __restrict__ ei, int* __restrict__ fmt,
                        int* __restrict__ ccnt, int nb16) {
    int i = blockIdx.x * 256 + threadIdx.x;
    if (i < nb16) ccnt[i] = 0;
    if (i == 0) {
        int f = 1;
        #pragma unroll
        for (int k = 1; k < 32; k += 2) if (ei[k] != 0) f = 0;
        *fmt = f;   // 1 => int64 (stride 2 in int32 words), 0 => int32
    }
}

// Coarse count: LDS histogram per block, then reserve per-(block,bucket) space
// with ONE padded global atomic per bucket per block (line-parallel).
__global__ void __launch_bounds__(256) k_coarse(
        const int* __restrict__ ei, const int* __restrict__ fmt,
        int* __restrict__ ccnt, int* __restrict__ blockbase, int E, int NB) {
    __shared__ int h[MAXNB];
    int sh = *fmt;
    for (int i = threadIdx.x; i < NB; i += 256) h[i] = 0;
    __syncthreads();
    for (long long e = (long long)blockIdx.x * 256 + threadIdx.x; e < E;
         e += (long long)A1G * 256) {
        int d = ei[(long long)(E + e) << sh];
        atomicAdd(&h[d >> 8], 1);
    }
    __syncthreads();
    for (int b = threadIdx.x; b < NB; b += 256) {
        int c = h[b];
        int base = (c > 0) ? atomicAdd(&ccnt[b * 16], c) : 0;
        blockbase[(long long)blockIdx.x * NB + b] = base;
    }
}

// Exclusive scan of the NB coarse counts (single block).
__global__ void __launch_bounds__(512) k_cscan(
        const int* __restrict__ ccnt, int* __restrict__ cstart, int NB) {
    __shared__ int s[512];
    int t = threadIdx.x;
    int c = (t < NB) ? ccnt[t * 16] : 0;
    s[t] = c;
    __syncthreads();
    for (int off = 1; off < 512; off <<= 1) {
        int v = s[t];
        int u = (t >= off) ? s[t - off] : 0;
        __syncthreads();
        s[t] = v + u;
        __syncthreads();
    }
    if (t < NB) cstart[t] = s[t] - c;
}

// Coarse scatter: same grid-stride partition as k_coarse, so this block's
// per-bucket totals equal its reservation. Edge packed as src|(dst&255)<<17.
__global__ void __launch_bounds__(256) k_cscatter(
        const int* __restrict__ ei, const int* __restrict__ fmt,
        const int* __restrict__ cstart, const int* __restrict__ blockbase,
        int* __restrict__ pairs, int E, int NB) {
    __shared__ int h[MAXNB];
    __shared__ int bb[MAXNB];
    int sh = *fmt;
    for (int i = threadIdx.x; i < NB; i += 256) {
        h[i] = 0;
        bb[i] = cstart[i] + blockbase[(long long)blockIdx.x * NB + i];
    }
    __syncthreads();
    for (long long e = (long long)blockIdx.x * 256 + threadIdx.x; e < E;
         e += (long long)A1G * 256) {
        int s = ei[(long long)e << sh];
        int d = ei[(long long)(E + e) << sh];
        int b = d >> 8;
        int r = atomicAdd(&h[b], 1);
        pairs[bb[b] + r] = s | ((d & 255) << 17);
    }
}

// Fine sort: one block per coarse bucket, entirely in LDS. Emits cnt/start/dis
// (coalesced) and esrc (scatter within the bucket's contiguous window).
__global__ void __launch_bounds__(256) k_bucket(
        const int* __restrict__ pairs, const int* __restrict__ ccnt,
        const int* __restrict__ cstart, int* __restrict__ esrc,
        int* __restrict__ cnt, int* __restrict__ start, float* __restrict__ dis,
        int N) {
    __shared__ int words[CAP];
    __shared__ unsigned char rk[CAP];
    __shared__ int h[NPB];
    __shared__ int hs[NPB];
    int b = blockIdx.x;
    int cs = cstart[b];
    int ec = ccnt[b * 16];
    if (ec > CAP) ec = CAP;          // memory-safety clamp (P ~ 0 for uniform dst)
    int t = threadIdx.x;
    for (int i = t; i < ec; i += 256) words[i] = pairs[cs + i];
    h[t] = 0;
    __syncthreads();
    for (int i = t; i < ec; i += 256) {
        int ld = words[i] >> 17;
        rk[i] = (unsigned char)atomicAdd(&h[ld], 1);
    }
    __syncthreads();
    int c = h[t];
    hs[t] = c;
    __syncthreads();
    for (int off = 1; off < 256; off <<= 1) {
        int v = hs[t];
        int u = (t >= off) ? hs[t - off] : 0;
        __syncthreads();
        hs[t] = v + u;               // inclusive scan
        __syncthreads();
    }
    int node = b * NPB + t;
    if (node < N) {
        cnt[node] = c;
        start[node] = cs + hs[t] - c;
        dis[node] = rsqrtf(1.0f + (float)c);   // degree includes self-loop
    }
    for (int i = t; i < ec; i += 256) {
        int w = words[i];
        int ld = w >> 17;
        esrc[cs + (hs[ld] - h[ld]) + rk[i]] = w & 0x1FFFF;
    }
}

// T16[n,NH] (int16) = quant_rowwise( dis[n] * (X[n,128] @ W[128,NH]) );
// rs[n] = rowmax/32767. 64 rows/block, 4x4 per thread; K split into two
// 64-wide phases with BOTH xs half AND Ws half (16KB) staged per phase:
// LDS ~34KB => 3 blocks/CU. KP3=68: pitch 272B (16B-aligned, mandatory for
// b128) and 4-row group offset = 16 banks => 2-way alias (free on gfx950).
#define KP3 68
__global__ void __launch_bounds__(256) k_gemm128(
        const float* __restrict__ X, const float* __restrict__ W,
        const float* __restrict__ dis, short* __restrict__ T16,
        float* __restrict__ rs, int n) {
    __shared__ float xs[64 * KP3];     // 17408 B
    __shared__ float Ws[64 * NH];      // 16384 B (one K-half of W)
    __shared__ int rmax[64];
    if (threadIdx.x < 64) rmax[threadIdx.x] = 0;
    long long rowbase = (long long)blockIdx.x * 64;
    int c0 = (threadIdx.x & 15) * 4;
    int r0 = (threadIdx.x >> 4) * 4;
    float4 a0{0,0,0,0}, a1{0,0,0,0}, a2{0,0,0,0}, a3{0,0,0,0};
    #pragma unroll
    for (int ph = 0; ph < 2; ++ph) {
        if (ph) __syncthreads();     // phase-0 compute done before overwrite
        // stage this K-half of W (rows ph*64..ph*64+63, contiguous 16KB)
        const float4* Wp4 = (const float4*)(W + (long long)ph * 64 * NH);
        for (int i = threadIdx.x; i < 64 * NH / 4; i += 256)
            ((float4*)Ws)[i] = Wp4[i];
        // stage this K-half of X rows
        const float* Xp = X + rowbase * NF + ph * 64;
        for (int i = threadIdx.x; i < 1024; i += 256) {
            int r = i >> 4, kk = (i & 15) << 2;
            float4 v = (rowbase + r < n)
                           ? *(const float4*)(Xp + r * NF + kk)
                           : make_float4(0.f, 0.f, 0.f, 0.f);
            *(float4*)&xs[r * KP3 + kk] = v;
        }
        __syncthreads();
        const float* x0 = &xs[(r0 + 0) * KP3];
        const float* x1 = &xs[(r0 + 1) * KP3];
        const float* x2 = &xs[(r0 + 2) * KP3];
        const float* x3 = &xs[(r0 + 3) * KP3];
        const float* Wp0 = &Ws[c0];
        #pragma unroll 4
        for (int k4 = 0; k4 < 16; ++k4) {
            float4 xv0 = *(const float4*)(x0 + k4 * 4);
            float4 xv1 = *(const float4*)(x1 + k4 * 4);
            float4 xv2 = *(const float4*)(x2 + k4 * 4);
            float4 xv3 = *(const float4*)(x3 + k4 * 4);
            float4 wa = *(const float4*)(Wp0 + (k4 * 4 + 0) * NH);
            float4 wb = *(const float4*)(Wp0 + (k4 * 4 + 1) * NH);
            float4 wc = *(const float4*)(Wp0 + (k4 * 4 + 2) * NH);
            float4 wd = *(const float4*)(Wp0 + (k4 * 4 + 3) * NH);
            // k4*4+0
            a0.x += xv0.x * wa.x; a0.y += xv0.x * wa.y; a0.z += xv0.x * wa.z; a0.w += xv0.x * wa.w;
            a1.x += xv1.x * wa.x; a1.y += xv1.x * wa.y; a1.z += xv1.x * wa.z; a1.w += xv1.x * wa.w;
            a2.x += xv2.x * wa.x; a2.y += xv2.x * wa.y; a2.z += xv2.x * wa.z; a2.w += xv2.x * wa.w;
            a3.x += xv3.x * wa.x; a3.y += xv3.x * wa.y; a3.z += xv3.x * wa.z; a3.w += xv3.x * wa.w;
            // k4*4+1
            a0.x += xv0.y * wb.x; a0.y += xv0.y * wb.y; a0.z += xv0.y * wb.z; a0.w += xv0.y * wb.w;
            a1.x += xv1.y * wb.x; a1.y += xv1.y * wb.y; a1.z += xv1.y * wb.z; a1.w += xv1.y * wb.w;
            a2.x += xv2.y * wb.x; a2.y += xv2.y * wb.y; a2.z += xv2.y * wb.z; a2.w += xv2.y * wb.w;
            a3.x += xv3.y * wb.x; a3.y += xv3.y * wb.y; a3.z += xv3.y * wb.z; a3.w += xv3.y * wb.w;
            // k4*4+2
            a0.x += xv0.z * wc.x; a0.y += xv0.z * wc.y; a0.z += xv0.z * wc.z; a0.w += xv0.z * wc.w;
            a1.x += xv1.z * wc.x; a1.y += xv1.z * wc.y; a1.z += xv1.z * wc.z; a1.w += xv1.z * wc.w;
            a2.x += xv2.z * wc.x; a2.y += xv2.z * wc.y; a2.z += xv2.z * wc.z; a2.w += xv2.z * wc.w;
            a3.x += xv3.z * wc.x; a3.y += xv3.z * wc.y; a3.z += xv3.z * wc.z; a3.w += xv3.z * wc.w;
            // k4*4+3
            a0.x += xv0.w * wd.x; a0.y += xv0.w * wd.y; a0.z += xv0.w * wd.z; a0.w += xv0.w * wd.w;
            a1.x += xv1.w * wd.x; a1.y += xv1.w * wd.y; a1.z += xv1.w * wd.z; a1.w += xv1.w * wd.w;
            a2.x += xv2.w * wd.x; a2.y += xv2.w * wd.y; a2.z += xv2.w * wd.z; a2.w += xv2.w * wd.w;
            a3.x += xv3.w * wd.x; a3.y += xv3.w * wd.y; a3.z += xv3.w * wd.z; a3.w += xv3.w * wd.w;
        }
    }
    int row = (int)rowbase + r0;
    float d0 = (row + 0 < n) ? dis[row + 0] : 0.0f;
    float d1 = (row + 1 < n) ? dis[row + 1] : 0.0f;
    float d2 = (row + 2 < n) ? dis[row + 2] : 0.0f;
    float d3 = (row + 3 < n) ? dis[row + 3] : 0.0f;
    a0.x *= d0; a0.y *= d0; a0.z *= d0; a0.w *= d0;
    a1.x *= d1; a1.y *= d1; a1.z *= d1; a1.w *= d1;
    a2.x *= d2; a2.y *= d2; a2.z *= d2; a2.w *= d2;
    a3.x *= d3; a3.y *= d3; a3.z *= d3; a3.w *= d3;
    float m0 = fmaxf(fmaxf(fabsf(a0.x), fabsf(a0.y)), fmaxf(fabsf(a0.z), fabsf(a0.w)));
    float m1 = fmaxf(fmaxf(fabsf(a1.x), fabsf(a1.y)), fmaxf(fabsf(a1.z), fabsf(a1.w)));
    float m2 = fmaxf(fmaxf(fabsf(a2.x), fabsf(a2.y)), fmaxf(fabsf(a2.z), fabsf(a2.w)));
    float m3 = fmaxf(fmaxf(fabsf(a3.x), fabsf(a3.y)), fmaxf(fabsf(a3.z), fabsf(a3.w)));
    atomicMax(&rmax[r0 + 0], __float_as_int(m0));
    atomicMax(&rmax[r0 + 1], __float_as_int(m1));
    atomicMax(&rmax[r0 + 2], __float_as_int(m2));
    atomicMax(&rmax[r0 + 3], __float_as_int(m3));
    __syncthreads();
    float M0 = __int_as_float(rmax[r0 + 0]);
    float M1 = __int_as_float(rmax[r0 + 1]);
    float M2 = __int_as_float(rmax[r0 + 2]);
    float M3 = __int_as_float(rmax[r0 + 3]);
    float i0 = 32767.0f / fmaxf(M0, 1e-20f);
    float i1 = 32767.0f / fmaxf(M1, 1e-20f);
    float i2 = 32767.0f / fmaxf(M2, 1e-20f);
    float i3 = 32767.0f / fmaxf(M3, 1e-20f);
    const float ks = 1.0f / 32767.0f;
    if (row + 0 < n) {
        short4 q = { (short)__float2int_rn(a0.x * i0), (short)__float2int_rn(a0.y * i0),
                     (short)__float2int_rn(a0.z * i0), (short)__float2int_rn(a0.w * i0) };
        *(short4*)&T16[(long long)(row + 0) * NH + c0] = q;
        if (c0 == 0) rs[row + 0] = M0 * ks;
    }
    if (row + 1 < n) {
        short4 q = { (short)__float2int_rn(a1.x * i1), (short)__float2int_rn(a1.y * i1),
                     (short)__float2int_rn(a1.z * i1), (short)__float2int_rn(a1.w * i1) };
        *(short4*)&T16[(long long)(row + 1) * NH + c0] = q;
        if (c0 == 0) rs[row + 1] = M1 * ks;
    }
    if (row + 2 < n) {
        short4 q = { (short)__float2int_rn(a2.x * i2), (short)__float2int_rn(a2.y * i2),
                     (short)__float2int_rn(a2.z * i2), (short)__float2int_rn(a2.w * i2) };
        *(short4*)&T16[(long long)(row + 2) * NH + c0] = q;
        if (c0 == 0) rs[row + 2] = M2 * ks;
    }
    if (row + 3 < n) {
        short4 q = { (short)__float2int_rn(a3.x * i3), (short)__float2int_rn(a3.y * i3),
                     (short)__float2int_rn(a3.z * i3), (short)__float2int_rn(a3.w * i3) };
        *(short4*)&T16[(long long)(row + 3) * NH + c0] = q;
        if (c0 == 0) rs[row + 3] = M3 * ks;
    }
}

// One A-edge / B-edge step: readlane word+scale bits, saddr int16 load, fma.
#define EDGE_A(J) {                                                           \
    int s_ = __builtin_amdgcn_readlane(sA, (J));                              \
    float f_ = __int_as_float(__builtin_amdgcn_readlane(fAb, (J)));           \
    accA = fmaf(f_, (float)(T + s_ * NH)[lane], accA); }
#define EDGE_B(J) {                                                           \
    int s_ = __builtin_amdgcn_readlane(sB, (J));                              \
    float f_ = __int_as_float(__builtin_amdgcn_readlane(fBb, (J)));           \
    accB = fmaf(f_, (float)(T + s_ * NH)[lane], accB); }

// Full-wave gather, TWO nodes per wave (A,B) with interleaved batches:
// the two batch prologues (esrc load + rs vector-gather) are independent
// chains and overlap; inner loop interleaves 4 A-edges + 4 B-edges.
#define SEG_GATHER2                                                           \
    int lane = threadIdx.x & 63;                                              \
    int na = blockIdx.x * 8 + (threadIdx.x >> 6) * 2;                         \
    int nb_ = na + 1;                                                         \
    if (na >= n) return;                                                      \
    bool hasB = (nb_ < n);                                                    \
    float dia = dis[na];                                                      \
    float dib = hasB ? dis[nb_] : 0.0f;                                       \
    int ga = cnt[na], sta = start[na];                                        \
    int gb = hasB ? cnt[nb_] : 0;                                             \
    int stb = hasB ? start[nb_] : 0;                                          \
    float accA = rs[na] * (float)T[na * NH + lane];                           \
    float accB = hasB ? rs[nb_] * (float)T[nb_ * NH + lane] : 0.0f;           \
    int gmax = ga > gb ? ga : gb;                                             \
    for (int base = 0; base < gmax; base += 64) {                             \
        int ma = ga - base; ma = ma < 0 ? 0 : (ma > 64 ? 64 : ma);            \
        int mb = gb - base; mb = mb < 0 ? 0 : (mb > 64 ? 64 : mb);            \
        int sA = 0, sB = 0; float fA = 0.0f, fB = 0.0f;                       \
        if (lane < ma) { sA = esrc[sta + base + lane]; fA = rs[sA]; }         \
        if (lane < mb) { sB = esrc[stb + base + lane]; fB = rs[sB]; }         \
        int fAb = __float_as_int(fA), fBb = __float_as_int(fB);               \
        int mmin = ma < mb ? ma : mb;                                         \
        int j = 0;                                                            \
        for (; j + 3 < mmin; j += 4) {                                        \
            EDGE_A(j + 0) EDGE_B(j + 0)                                       \
            EDGE_A(j + 1) EDGE_B(j + 1)                                       \
            EDGE_A(j + 2) EDGE_B(j + 2)                                       \
            EDGE_A(j + 3) EDGE_B(j + 3)                                       \
        }                                                                     \
        int jA = j, jB = j;                                                   \
        for (; jA + 3 < ma; jA += 4) {                                        \
            EDGE_A(jA + 0) EDGE_A(jA + 1) EDGE_A(jA + 2) EDGE_A(jA + 3)       \
        }                                                                     \
        for (; jA < ma; ++jA) EDGE_A(jA)                                      \
        for (; jB + 3 < mb; jB += 4) {                                        \
            EDGE_B(jB + 0) EDGE_B(jB + 1) EDGE_B(jB + 2) EDGE_B(jB + 3)       \
        }                                                                     \
        for (; jB < mb; ++jB) EDGE_B(jB)                                      \
    }

// Layer-0 gather + FUSED layer-1 transform/quant (replaces k_seg + k_gemm<64>):
// h0[lane] = dia*acc + b0[lane] (full row held one channel per lane);
// o[lane] = sum_c h0[c]*W1[c][lane] via readlane broadcast vs conflict-free
// stride-1 LDS W1 reads (16KB staged once per block; keeps VGPR ~24 so
// gather occupancy stays ~8 waves/SIMD). Even/odd accumulator split halves
// the fma dependence depth. Then dis-scale + rowwise int16 quant in-wave.
__global__ void __launch_bounds__(256) k_seg0t(
        const short* __restrict__ T, const float* __restrict__ rs,
        const int* __restrict__ esrc, const int* __restrict__ start,
        const int* __restrict__ cnt, const float* __restrict__ dis,
        const float* __restrict__ b0, const float* __restrict__ W1,
        short* __restrict__ To, float* __restrict__ rso, int n) {
    __shared__ float W1s[NH * NH];
    for (int i = threadIdx.x; i < NH * NH / 4; i += 256)
        ((float4*)W1s)[i] = ((const float4*)W1)[i];
    __syncthreads();      // before any early return (divergent-exit barrier UB)
    SEG_GATHER2
    float bv = b0[lane];
    float hA = dia * accA + bv;
    float hB = dib * accB + bv;      // dib==0 when !hasB (result unused)
    float oA0 = 0.0f, oA1 = 0.0f, oB0 = 0.0f, oB1 = 0.0f;
    #pragma unroll
    for (int c = 0; c < 64; c += 2) {
        float wv0 = W1s[(c + 0) * NH + lane];
        float wv1 = W1s[(c + 1) * NH + lane];
        float ha0 = __int_as_float(__builtin_amdgcn_readlane(__float_as_int(hA), c + 0));
        float ha1 = __int_as_float(__builtin_amdgcn_readlane(__float_as_int(hA), c + 1));
        float hb0 = __int_as_float(__builtin_amdgcn_readlane(__float_as_int(hB), c + 0));
        float hb1 = __int_as_float(__builtin_amdgcn_readlane(__float_as_int(hB), c + 1));
        oA0 = fmaf(ha0, wv0, oA0);
        oA1 = fmaf(ha1, wv1, oA1);
        oB0 = fmaf(hb0, wv0, oB0);
        oB1 = fmaf(hb1, wv1, oB1);
    }
    float oA = (oA0 + oA1) * dia;
    float oB = (oB0 + oB1) * dib;
    float mA = fabsf(oA), mB = fabsf(oB);
    #pragma unroll
    for (int msk = 32; msk; msk >>= 1) {
        mA = fmaxf(mA, __shfl_xor(mA, msk, 64));
        mB = fmaxf(mB, __shfl_xor(mB, msk, 64));
    }
    float iA = 32767.0f / fmaxf(mA, 1e-20f);
    float iB = 32767.0f / fmaxf(mB, 1e-20f);
    const float ks = 1.0f / 32767.0f;
    To[(long long)na * NH + lane] = (short)__float2int_rn(oA * iA);
    if (lane == 0) rso[na] = mA * ks;
    if (hasB) {
        To[(long long)nb_ * NH + lane] = (short)__float2int_rn(oB * iB);
        if (lane == 0) rso[nb_] = mB * ks;
    }
}

// Layer-1 + fused layer-2 transform for both nodes: z1[c]=di*acc+b1[c];
// t=tanh(z1); t2 = di*(t @ W2) via 6-step full-wave butterfly (per node).
__global__ void __launch_bounds__(256) k_seg1f(
        const short* __restrict__ T, const float* __restrict__ rs,
        const int* __restrict__ esrc, const int* __restrict__ start,
        const int* __restrict__ cnt, const float* __restrict__ dis,
        const float* __restrict__ b1, const float* __restrict__ W2,
        float2* __restrict__ t2, int n) {
    SEG_GATHER2
    float bv = b1[lane];
    float2 w = ((const float2*)W2)[lane];   // W2[lane][0], W2[lane][1]
    float tA = tanhf(dia * accA + bv);
    float p0 = tA * w.x, p1 = tA * w.y;
    float tB = hasB ? tanhf(dib * accB + bv) : 0.0f;
    float q0 = tB * w.x, q1 = tB * w.y;
    #pragma unroll
    for (int msk = 32; msk; msk >>= 1) {
        p0 += __shfl_xor(p0, msk, 64);
        p1 += __shfl_xor(p1, msk, 64);
        q0 += __shfl_xor(q0, msk, 64);
        q1 += __shfl_xor(q1, msk, 64);
    }
    if (lane == 0) {
        t2[na] = make_float2(dia * p0, dia * p1);
        if (hasB) t2[nb_] = make_float2(dib * q0, dib * q1);
    }
}

// Fused layer-2 aggregation + head, 16 LANES PER NODE (4 nodes/wave):
// lane-parallel edge loads (depth ~1 instead of ~16 serial per thread),
// 4-step shfl_xor reduce within the 16-lane group, then lanes 0-3 of the
// group each write 4 of the 16 output channels.
__global__ void __launch_bounds__(256) k_seg2f(
        const float2* __restrict__ T2, const int* __restrict__ esrc,
        const int* __restrict__ start, const int* __restrict__ cnt,
        const float* __restrict__ dis, const float* __restrict__ b2,
        const float* __restrict__ Wc, const float* __restrict__ bc,
        float* __restrict__ out, float* __restrict__ emb, int n) {
    int lane = threadIdx.x & 63;
    int sub = lane >> 4;           // node slot within the wave
    int sl = lane & 15;            // lane within the node's 16-lane group
    int i = blockIdx.x * 16 + (threadIdx.x >> 6) * 4 + sub;
    if (i >= n) return;            // whole 16-lane group exits together
    float di = dis[i];
    int g = cnt[i], st = start[i];
    float a0 = 0.0f, a1 = 0.0f;
    for (int j = sl; j < g; j += 16) {
        float2 v = T2[esrc[st + j]];
        a0 += v.x; a1 += v.y;
    }
    if (sl == 0) {
        float2 s = T2[i];
        a0 += s.x; a1 += s.y;
    }
    #pragma unroll
    for (int msk = 8; msk; msk >>= 1) {
        a0 += __shfl_xor(a0, msk, 64);
        a1 += __shfl_xor(a1, msk, 64);
    }
    float e0 = tanhf(a0 * di + b2[0]);
    float e1 = tanhf(a1 * di + b2[1]);
    if (sl == 0) *(float2*)&emb[(long long)i * 2] = make_float2(e0, e1);
    if (sl < 4) {
        int c = sl * 4;
        float4 o;
        o.x = e0 * Wc[c + 0] + e1 * Wc[16 + c + 0] + bc[c + 0];
        o.y = e0 * Wc[c + 1] + e1 * Wc[16 + c + 1] + bc[c + 1];
        o.z = e0 * Wc[c + 2] + e1 * Wc[16 + c + 2] + bc[c + 2];
        o.w = e0 * Wc[c + 3] + e1 * Wc[16 + c + 3] + bc[c + 3];
        *(float4*)&out[(long long)i * 16 + c] = o;
    }
}

extern "C" void kernel_launch(void* const* d_in, const int* in_sizes, int n_in,
                              void* d_out, int out_size, void* d_ws, size_t ws_size,
                              hipStream_t stream) {
    const float* x  = (const float*)d_in[0];
    const int*   ei = (const int*)  d_in[1];
    const float* W0 = (const float*)d_in[2];
    const float* b0 = (const float*)d_in[3];
    const float* W1 = (const float*)d_in[4];
    const float* b1 = (const float*)d_in[5];
    const float* W2 = (const float*)d_in[6];
    const float* b2 = (const float*)d_in[7];
    const float* Wc = (const float*)d_in[8];
    const float* bc = (const float*)d_in[9];

    int N = in_sizes[0] / NF;
    int E = in_sizes[1] / 2;
    int NB = (N + NPB - 1) / NPB;   // 391 for N=100000 (must be <= MAXNB)

    float* out = (float*)d_out;                    // [N,16]
    float* emb = out + (long long)N * 16;          // [N,2]

    // workspace: T16a[N*64 int16 = 12.8MB] | region2[N*64 fp32 = 25.6MB] |
    //            dis[N] | rs_a[N] | cnt[N] | start[N] | esrc[E] | fmt
    // region2 holds the layer-1 quant row T16b (12.8MB) + t2 (0.8MB) + rs_b
    // (0.4MB) -- T16a must stay live while k_seg0t gathers from it.
    // Preprocessing scratch (pairs/blockbase/ccnt/cstart ~ 8MB) overlays T16a
    // (dead until the first k_gemm128).
    short*  T16a = (short*)d_ws;
    char*   r2   = (char*)d_ws + (long long)N * NH * 2;
    short*  T16b = (short*)r2;
    float2* t2   = (float2*)(r2 + (long long)N * NH * 2);
    float*  rs_b = (float*)(r2 + (long long)N * NH * 2 + (long long)N * 8);
    float*  dis  = (float*)((char*)d_ws + (long long)N * NH * 2 + (long long)N * NH * 4);
    float*  rs_a = dis + N;
    int*    cnt   = (int*)(rs_a + N);
    int*    start = cnt + N;
    int*    esrc  = start + N;
    int*    fmt   = esrc + E;

    int* pairs     = (int*)d_ws;                       // E ints (overlay T16a)
    int* blockbase = pairs + E;                        // A1G * NB
    int* ccnt      = blockbase + (long long)A1G * NB;  // NB*16 (line-padded)
    int* cstart    = ccnt + NB * 16;                   // NB

    int nb_g  = (N + 63) / 64;
    int nb_s2 = (N + 7) / 8;
    int nb_2f = (N + 15) / 16;
    int nb_i0 = (NB * 16 + 255) / 256;

    // per-call two-level bucket sort (inputs restored before every call)
    k_init0   <<<nb_i0, 256, 0, stream>>>(ei, fmt, ccnt, NB * 16);
    k_coarse  <<<A1G, 256, 0, stream>>>(ei, fmt, ccnt, blockbase, E, NB);
    k_cscan   <<<1, 512, 0, stream>>>(ccnt, cstart, NB);
    k_cscatter<<<A1G, 256, 0, stream>>>(ei, fmt, cstart, blockbase, pairs, E, NB);
    k_bucket  <<<NB, 256, 0, stream>>>(pairs, ccnt, cstart, esrc, cnt, start, dis, N);

    // layer 0: fused gemm + rowwise int16 quant
    k_gemm128 <<<nb_g, 256, 0, stream>>>(x, W0, dis, T16a, rs_a, N);

    // layer-0 gather + fused layer-1 transform/quant (k_gemm<64> eliminated)
    k_seg0t   <<<nb_s2, 256, 0, stream>>>(T16a, rs_a, esrc, start, cnt, dis, b0,
                                          W1, T16b, rs_b, N);

    // layer 1 gather + fused layer-2 transform (tanh + @W2 in epilogue)
    k_seg1f   <<<nb_s2, 256, 0, stream>>>(T16b, rs_b, esrc, start, cnt, dis, b1,
                                          W2, t2, N);

    // layer-2 aggregation + head (16 lanes per node)
    k_seg2f   <<<nb_2f, 256, 0, stream>>>(t2, esrc, start, cnt, dis, b2, Wc, bc,
                                          out, emb, N);
}

// Round 7
// 316.793 us; speedup vs baseline: 1.1369x; 1.0456x over previous
//
#include <hip/hip_runtime.h>

// GCN forward: 3x GCNConv (128->64->64->2) + linear head (2->16).
// N=100000 nodes, E=1600000 edges (+self-loops handled analytically).
// Preprocessing: two-level LDS bucket sort. Aggregation: atomic-free
// FULL-WAVE segment-sum gathers (lane = channel) over int16 rows with
// per-row scales; TWO nodes per wave interleaved.
// Round 23: round-22 MFMA layer-0 transform with the staging bug FIXED:
//  - Wf is 32KB = 2048 int4; round-22 staged only 1024 (u<4) -> lo-half
//    of LDS uninitialized -> NaN. Now u<8. (Layout theory unfalsified.)
//  - f16 split-precision (x = hi + lo, 3 MFMA: hi*whi + hi*wlo + lo*whi;
//    dropped lo*wlo ~ 2^-24 rel, far below int16 quant grain 3e-5).
//    mfma_f32_16x16x32_f16; C/D map col=lane&15,row=(lane>>4)*4+reg
//    (m89-verified); k-permutation inside fragments cancels (same map
//    used for A and B), so only row/col lane maps are load-bearing.
//  - W0 fragments precomputed once (k_wprep, 16 blocks) into a 32KB global
//    buffer overlaid on the dead T16b region; staged to LDS linearly.
//  - Old VALU gemm128 ran at ~31 TF (<=20% fp32 peak), MfmaUtil 0.
// Round-21 state kept verbatim elsewhere (best verified total 331.25us):
// seg0t 73.3us (VALUBusy 73%, occ 72%), seg1f ~49, seg2f 16-lane form.
// REGIME NOTE (r20 measured): gather kernels are RANDOM-ROW-TRAFFIC bound
// (~1.4-1.8 TB/s fabric on 128B rows); int16 rows ARE the bandwidth opt.
// BANNED (measured failures): half-wave/2-rows-per-load gather (~3e-3 absmax,
// r7-9/11); SGPR-indexed rs[] (s_load thrash, r13); LDS float atomicAdd
// (CAS storm, r15); LDS row pitch not 0 mod 16B in float4 tiles (r17);
// 64-entry per-lane VGPR arrays in gather kernels (occupancy halved, r17);
// persistent grid-stride gather blocks (load imbalance + VGPR, r19);
// fp32 pre-scaled gather rows (2x traffic on traffic-bound gather, r20);
// partial LDS staging loops -- verify element counts against buffer size (r22).
// dis[] pre-folded: T'[v]=dis[v]*t[v] => O[i]=dis[i]*(T'[i]+sum T'[s])+b.

#define NF 128
#define NH 64
#define NPB 256      // nodes per coarse bucket (bucket = dst >> 8)
#define MAXNB 512    // max coarse buckets (N < 131072, matches 17-bit src pack)
#define CAP 6144     // max edges per coarse bucket (mean 4096, >30 sigma)
#define A1G 1024     // grid for coarse count/scatter (must match between them)

typedef _Float16 half8 __attribute__((ext_vector_type(8)));
typedef float f32x4 __attribute__((ext_vector_type(4)));

// Zero coarse counters + detect int64 vs int32 edge_index layout.
__global__ void k_init0(const int* __restrict__ ei, int* __restrict__ fmt,
                        int* __restrict__ ccnt, int nb16) {
    int i = blockIdx.x * 256 + threadIdx.x;
    if (i < nb16) ccnt[i] = 0;
    if (i == 0) {
        int f = 1;
        #pragma unroll
        for (int k = 1; k < 32; k += 2) if (ei[k] != 0) f = 0;
        *fmt = f;   // 1 => int64 (stride 2 in int32 words), 0 => int32
    }
}

// Coarse count: LDS histogram per block, then reserve per-(block,bucket) space
// with ONE padded global atomic per bucket per block (line-parallel).
__global__ void __launch_bounds__(256) k_coarse(
        const int* __restrict__ ei, const int* __restrict__ fmt,
        int* __restrict__ ccnt, int* __restrict__ blockbase, int E, int NB) {
    __shared__ int h[MAXNB];
    int sh = *fmt;
    for (int i = threadIdx.x; i < NB; i += 256) h[i] = 0;
    __syncthreads();
    for (long long e = (long long)blockIdx.x * 256 + threadIdx.x; e < E;
         e += (long long)A1G * 256) {
        int d = ei[(long long)(E + e) << sh];
        atomicAdd(&h[d >> 8], 1);
    }
    __syncthreads();
    for (int b = threadIdx.x; b < NB; b += 256) {
        int c = h[b];
        int base = (c > 0) ? atomicAdd(&ccnt[b * 16], c) : 0;
        blockbase[(long long)blockIdx.x * NB + b] = base;
    }
}

// Exclusive scan of the NB coarse counts (single block).
__global__ void __launch_bounds__(512) k_cscan(
        const int* __restrict__ ccnt, int* __restrict__ cstart, int NB) {
    __shared__ int s[512];
    int t = threadIdx.x;
    int c = (t < NB) ? ccnt[t * 16] : 0;
    s[t] = c;
    __syncthreads();
    for (int off = 1; off < 512; off <<= 1) {
        int v = s[t];
        int u = (t >= off) ? s[t - off] : 0;
        __syncthreads();
        s[t] = v + u;
        __syncthreads();
    }
    if (t < NB) cstart[t] = s[t] - c;
}

// Coarse scatter: same grid-stride partition as k_coarse, so this block's
// per-bucket totals equal its reservation. Edge packed as src|(dst&255)<<17.
__global__ void __launch_bounds__(256) k_cscatter(
        const int* __restrict__ ei, const int* __restrict__ fmt,
        const int* __restrict__ cstart, const int* __restrict__ blockbase,
        int* __restrict__ pairs, int E, int NB) {
    __shared__ int h[MAXNB];
    __shared__ int bb[MAXNB];
    int sh = *fmt;
    for (int i = threadIdx.x; i < NB; i += 256) {
        h[i] = 0;
        bb[i] = cstart[i] + blockbase[(long long)blockIdx.x * NB + i];
    }
    __syncthreads();
    for (long long e = (long long)blockIdx.x * 256 + threadIdx.x; e < E;
         e += (long long)A1G * 256) {
        int s = ei[(long long)e << sh];
        int d = ei[(long long)(E + e) << sh];
        int b = d >> 8;
        int r = atomicAdd(&h[b], 1);
        pairs[bb[b] + r] = s | ((d & 255) << 17);
    }
}

// Fine sort: one block per coarse bucket, entirely in LDS. Emits cnt/start/dis
// (coalesced) and esrc (scatter within the bucket's contiguous window).
__global__ void __launch_bounds__(256) k_bucket(
        const int* __restrict__ pairs, const int* __restrict__ ccnt,
        const int* __restrict__ cstart, int* __restrict__ esrc,
        int* __restrict__ cnt, int* __restrict__ start, float* __restrict__ dis,
        int N) {
    __shared__ int words[CAP];
    __shared__ unsigned char rk[CAP];
    __shared__ int h[NPB];
    __shared__ int hs[NPB];
    int b = blockIdx.x;
    int cs = cstart[b];
    int ec = ccnt[b * 16];
    if (ec > CAP) ec = CAP;          // memory-safety clamp (P ~ 0 for uniform dst)
    int t = threadIdx.x;
    for (int i = t; i < ec; i += 256) words[i] = pairs[cs + i];
    h[t] = 0;
    __syncthreads();
    for (int i = t; i < ec; i += 256) {
        int ld = words[i] >> 17;
        rk[i] = (unsigned char)atomicAdd(&h[ld], 1);
    }
    __syncthreads();
    int c = h[t];
    hs[t] = c;
    __syncthreads();
    for (int off = 1; off < 256; off <<= 1) {
        int v = hs[t];
        int u = (t >= off) ? hs[t - off] : 0;
        __syncthreads();
        hs[t] = v + u;               // inclusive scan
        __syncthreads();
    }
    int node = b * NPB + t;
    if (node < N) {
        cnt[node] = c;
        start[node] = cs + hs[t] - c;
        dis[node] = rsqrtf(1.0f + (float)c);   // degree includes self-loop
    }
    for (int i = t; i < ec; i += 256) {
        int w = words[i];
        int ld = w >> 17;
        esrc[cs + (hs[ld] - h[ld]) + rk[i]] = w & 0x1FFFF;
    }
}

// Precompute W0 MFMA B-fragments (f16 hi/lo), fragment-ordered so each lane
// reads its 8 halves with one b128. Entry (kc,ct,lane,j):
//   k = kc*32 + (lane>>4)*8 + j, col = ct*16 + (lane&15)  [B col = lane&15]
// wf[((kc*4+ct)*64+lane)*8 + j] = hi;  +8192 = lo.  Total 32KB.
__global__ void k_wprep(const float* __restrict__ W, short* __restrict__ wf) {
    int b = blockIdx.x;            // 0..15 = kc*4 + ct
    int kc = b >> 2, ct = b & 3;
    int t = threadIdx.x;
    int lane = t & 63;
    int j0 = (t >> 6) * 2;
    #pragma unroll
    for (int jj = 0; jj < 2; ++jj) {
        int j = j0 + jj;
        int k = kc * 32 + (lane >> 4) * 8 + j;
        int col = ct * 16 + (lane & 15);
        float w = W[k * NH + col];
        _Float16 h = (_Float16)w;
        _Float16 l = (_Float16)(w - (float)h);
        int idx = (b * 64 + lane) * 8 + j;
        wf[idx] = *(short*)&h;
        wf[idx + 8192] = *(short*)&l;
    }
}

// Layer-0 transform on MATRIX CORES: T16 = quant_rowwise(dis * (X @ W0)).
// 64 rows/block, 4 waves, one 16-row tile per wave. f16 split-precision:
// acc += ahi*bhi + ahi*blo + alo*bhi (3 MFMA per (kc,ct)); 48 MFMA/wave.
// X staged to LDS in two 64-col phases (KPX=68: 16B-aligned pitch, mandatory;
// A-frag read banks (4*(lane&15)+8*(lane>>4))%32 ~ 2x min alias, ok).
// W fragments staged once (32KB = 2048 int4 -- full count! r22 bug). LDS
// 49.4KB => 3 blocks/CU.
#define KPX 68
__global__ void __launch_bounds__(256) k_gemmM(
        const float* __restrict__ X, const short* __restrict__ wfrag,
        const float* __restrict__ dis, short* __restrict__ T16,
        float* __restrict__ rs, int n) {
    __shared__ __align__(16) short Wf[16384];   // 32KB: [hi 8192][lo 8192]
    __shared__ __align__(16) float xs[64 * KPX];
    int tid = threadIdx.x;
    {   // stage W fragments (once): 16384 shorts = 2048 int4
        const int4* src = (const int4*)wfrag;
        int4* dst = (int4*)Wf;
        #pragma unroll
        for (int u = 0; u < 8; ++u) dst[tid + u * 256] = src[tid + u * 256];
    }
    long long rowbase = (long long)blockIdx.x * 64;
    int lane = tid & 63;
    int wid = tid >> 6;
    f32x4 acc0 = {0,0,0,0}, acc1 = {0,0,0,0}, acc2 = {0,0,0,0}, acc3 = {0,0,0,0};
    #pragma unroll
    for (int ph = 0; ph < 2; ++ph) {
        __syncthreads();           // ph0: Wf visible; ph1: compute done
        const float* Xp = X + rowbase * NF + ph * 64;
        #pragma unroll
        for (int u = 0; u < 4; ++u) {
            int i = tid + u * 256;
            int r = i >> 4, kk = (i & 15) << 2;
            float4 v = (rowbase + r < n)
                           ? *(const float4*)(Xp + r * NF + kk)
                           : make_float4(0.f, 0.f, 0.f, 0.f);
            *(float4*)&xs[r * KPX + kk] = v;
        }
        __syncthreads();           // xs visible
        #pragma unroll
        for (int kcl = 0; kcl < 2; ++kcl) {
            const float* xp =
                &xs[(wid * 16 + (lane & 15)) * KPX + kcl * 32 + (lane >> 4) * 8];
            float4 xa = *(const float4*)xp;
            float4 xb = *(const float4*)(xp + 4);
            float xv[8] = {xa.x, xa.y, xa.z, xa.w, xb.x, xb.y, xb.z, xb.w};
            half8 ah, al;
            #pragma unroll
            for (int e = 0; e < 8; ++e) {
                _Float16 h = (_Float16)xv[e];
                ah[e] = h;
                al[e] = (_Float16)(xv[e] - (float)h);
            }
            int kc = ph * 2 + kcl;
            {
                const half8 bh = *(const half8*)&Wf[((kc * 4 + 0) * 64 + lane) * 8];
                const half8 bl = *(const half8*)&Wf[((kc * 4 + 0) * 64 + lane) * 8 + 8192];
                acc0 = __builtin_amdgcn_mfma_f32_16x16x32_f16(ah, bh, acc0, 0, 0, 0);
                acc0 = __builtin_amdgcn_mfma_f32_16x16x32_f16(ah, bl, acc0, 0, 0, 0);
                acc0 = __builtin_amdgcn_mfma_f32_16x16x32_f16(al, bh, acc0, 0, 0, 0);
            }
            {
                const half8 bh = *(const half8*)&Wf[((kc * 4 + 1) * 64 + lane) * 8];
                const half8 bl = *(const half8*)&Wf[((kc * 4 + 1) * 64 + lane) * 8 + 8192];
                acc1 = __builtin_amdgcn_mfma_f32_16x16x32_f16(ah, bh, acc1, 0, 0, 0);
                acc1 = __builtin_amdgcn_mfma_f32_16x16x32_f16(ah, bl, acc1, 0, 0, 0);
                acc1 = __builtin_amdgcn_mfma_f32_16x16x32_f16(al, bh, acc1, 0, 0, 0);
            }
            {
                const half8 bh = *(const half8*)&Wf[((kc * 4 + 2) * 64 + lane) * 8];
                const half8 bl = *(const half8*)&Wf[((kc * 4 + 2) * 64 + lane) * 8 + 8192];
                acc2 = __builtin_amdgcn_mfma_f32_16x16x32_f16(ah, bh, acc2, 0, 0, 0);
                acc2 = __builtin_amdgcn_mfma_f32_16x16x32_f16(ah, bl, acc2, 0, 0, 0);
                acc2 = __builtin_amdgcn_mfma_f32_16x16x32_f16(al, bh, acc2, 0, 0, 0);
            }
            {
                const half8 bh = *(const half8*)&Wf[((kc * 4 + 3) * 64 + lane) * 8];
                const half8 bl = *(const half8*)&Wf[((kc * 4 + 3) * 64 + lane) * 8 + 8192];
                acc3 = __builtin_amdgcn_mfma_f32_16x16x32_f16(ah, bh, acc3, 0, 0, 0);
                acc3 = __builtin_amdgcn_mfma_f32_16x16x32_f16(ah, bl, acc3, 0, 0, 0);
                acc3 = __builtin_amdgcn_mfma_f32_16x16x32_f16(al, bh, acc3, 0, 0, 0);
            }
        }
    }
    // Epilogue: lane holds D[(lane>>4)*4 + r][ct*16 + (lane&15)] (m89 map).
    int rb = (int)rowbase + wid * 16 + (lane >> 4) * 4;
    float dr0 = (rb + 0 < n) ? dis[rb + 0] : 0.0f;
    float dr1 = (rb + 1 < n) ? dis[rb + 1] : 0.0f;
    float dr2 = (rb + 2 < n) ? dis[rb + 2] : 0.0f;
    float dr3 = (rb + 3 < n) ? dis[rb + 3] : 0.0f;
    float drs[4] = {dr0, dr1, dr2, dr3};
    const float ks = 1.0f / 32767.0f;
    int cb = lane & 15;
    #pragma unroll
    for (int r = 0; r < 4; ++r) {
        float v0 = acc0[r] * drs[r];
        float v1 = acc1[r] * drs[r];
        float v2 = acc2[r] * drs[r];
        float v3 = acc3[r] * drs[r];
        float m = fmaxf(fmaxf(fabsf(v0), fabsf(v1)), fmaxf(fabsf(v2), fabsf(v3)));
        m = fmaxf(m, __shfl_xor(m, 1, 64));
        m = fmaxf(m, __shfl_xor(m, 2, 64));
        m = fmaxf(m, __shfl_xor(m, 4, 64));
        m = fmaxf(m, __shfl_xor(m, 8, 64));
        float ir = 32767.0f / fmaxf(m, 1e-20f);
        int rowg = rb + r;
        if (rowg < n) {
            long long base = (long long)rowg * NH;
            T16[base + 0  + cb] = (short)__float2int_rn(v0 * ir);
            T16[base + 16 + cb] = (short)__float2int_rn(v1 * ir);
            T16[base + 32 + cb] = (short)__float2int_rn(v2 * ir);
            T16[base + 48 + cb] = (short)__float2int_rn(v3 * ir);
            if (cb == 0) rs[rowg] = m * ks;
        }
    }
}

// One A-edge / B-edge step: readlane word+scale bits, saddr int16 load, fma.
#define EDGE_A(J) {                                                           \
    int s_ = __builtin_amdgcn_readlane(sA, (J));                              \
    float f_ = __int_as_float(__builtin_amdgcn_readlane(fAb, (J)));           \
    accA = fmaf(f_, (float)(T + s_ * NH)[lane], accA); }
#define EDGE_B(J) {                                                           \
    int s_ = __builtin_amdgcn_readlane(sB, (J));                              \
    float f_ = __int_as_float(__builtin_amdgcn_readlane(fBb, (J)));           \
    accB = fmaf(f_, (float)(T + s_ * NH)[lane], accB); }

// Full-wave gather, TWO nodes per wave (A,B) with interleaved batches:
// the two batch prologues (esrc load + rs vector-gather) are independent
// chains and overlap; inner loop interleaves 4 A-edges + 4 B-edges.
#define SEG_GATHER2                                                           \
    int lane = threadIdx.x & 63;                                              \
    int na = blockIdx.x * 8 + (threadIdx.x >> 6) * 2;                         \
    int nb_ = na + 1;                                                         \
    if (na >= n) return;                                                      \
    bool hasB = (nb_ < n);                                                    \
    float dia = dis[na];                                                      \
    float dib = hasB ? dis[nb_] : 0.0f;                                       \
    int ga = cnt[na], sta = start[na];                                        \
    int gb = hasB ? cnt[nb_] : 0;                                             \
    int stb = hasB ? start[nb_] : 0;                                          \
    float accA = rs[na] * (float)T[na * NH + lane];                           \
    float accB = hasB ? rs[nb_] * (float)T[nb_ * NH + lane] : 0.0f;           \
    int gmax = ga > gb ? ga : gb;                                             \
    for (int base = 0; base < gmax; base += 64) {                             \
        int ma = ga - base; ma = ma < 0 ? 0 : (ma > 64 ? 64 : ma);            \
        int mb = gb - base; mb = mb < 0 ? 0 : (mb > 64 ? 64 : mb);            \
        int sA = 0, sB = 0; float fA = 0.0f, fB = 0.0f;                       \
        if (lane < ma) { sA = esrc[sta + base + lane]; fA = rs[sA]; }         \
        if (lane < mb) { sB = esrc[stb + base + lane]; fB = rs[sB]; }         \
        int fAb = __float_as_int(fA), fBb = __float_as_int(fB);               \
        int mmin = ma < mb ? ma : mb;                                         \
        int j = 0;                                                            \
        for (; j + 3 < mmin; j += 4) {                                        \
            EDGE_A(j + 0) EDGE_B(j + 0)                                       \
            EDGE_A(j + 1) EDGE_B(j + 1)                                       \
            EDGE_A(j + 2) EDGE_B(j + 2)                                       \
            EDGE_A(j + 3) EDGE_B(j + 3)                                       \
        }                                                                     \
        int jA = j, jB = j;                                                   \
        for (; jA + 3 < ma; jA += 4) {                                        \
            EDGE_A(jA + 0) EDGE_A(jA + 1) EDGE_A(jA + 2) EDGE_A(jA + 3)       \
        }                                                                     \
        for (; jA < ma; ++jA) EDGE_A(jA)                                      \
        for (; jB + 3 < mb; jB += 4) {                                        \
            EDGE_B(jB + 0) EDGE_B(jB + 1) EDGE_B(jB + 2) EDGE_B(jB + 3)       \
        }                                                                     \
        for (; jB < mb; ++jB) EDGE_B(jB)                                      \
    }

// Layer-0 gather + FUSED layer-1 transform/quant (replaces k_seg + k_gemm<64>):
// h0[lane] = dia*acc + b0[lane] (full row held one channel per lane);
// o[lane] = sum_c h0[c]*W1[c][lane] via readlane broadcast vs conflict-free
// stride-1 LDS W1 reads (16KB staged once per block; keeps VGPR ~24 so
// gather occupancy stays ~8 waves/SIMD). Even/odd accumulator split halves
// the fma dependence depth. Then dis-scale + rowwise int16 quant in-wave.
__global__ void __launch_bounds__(256) k_seg0t(
        const short* __restrict__ T, const float* __restrict__ rs,
        const int* __restrict__ esrc, const int* __restrict__ start,
        const int* __restrict__ cnt, const float* __restrict__ dis,
        const float* __restrict__ b0, const float* __restrict__ W1,
        short* __restrict__ To, float* __restrict__ rso, int n) {
    __shared__ float W1s[NH * NH];
    for (int i = threadIdx.x; i < NH * NH / 4; i += 256)
        ((float4*)W1s)[i] = ((const float4*)W1)[i];
    __syncthreads();      // before any early return (divergent-exit barrier UB)
    SEG_GATHER2
    float bv = b0[lane];
    float hA = dia * accA + bv;
    float hB = dib * accB + bv;      // dib==0 when !hasB (result unused)
    float oA0 = 0.0f, oA1 = 0.0f, oB0 = 0.0f, oB1 = 0.0f;
    #pragma unroll
    for (int c = 0; c < 64; c += 2) {
        float wv0 = W1s[(c + 0) * NH + lane];
        float wv1 = W1s[(c + 1) * NH + lane];
        float ha0 = __int_as_float(__builtin_amdgcn_readlane(__float_as_int(hA), c + 0));
        float ha1 = __int_as_float(__builtin_amdgcn_readlane(__float_as_int(hA), c + 1));
        float hb0 = __int_as_float(__builtin_amdgcn_readlane(__float_as_int(hB), c + 0));
        float hb1 = __int_as_float(__builtin_amdgcn_readlane(__float_as_int(hB), c + 1));
        oA0 = fmaf(ha0, wv0, oA0);
        oA1 = fmaf(ha1, wv1, oA1);
        oB0 = fmaf(hb0, wv0, oB0);
        oB1 = fmaf(hb1, wv1, oB1);
    }
    float oA = (oA0 + oA1) * dia;
    float oB = (oB0 + oB1) * dib;
    float mA = fabsf(oA), mB = fabsf(oB);
    #pragma unroll
    for (int msk = 32; msk; msk >>= 1) {
        mA = fmaxf(mA, __shfl_xor(mA, msk, 64));
        mB = fmaxf(mB, __shfl_xor(mB, msk, 64));
    }
    float iA = 32767.0f / fmaxf(mA, 1e-20f);
    float iB = 32767.0f / fmaxf(mB, 1e-20f);
    const float ks = 1.0f / 32767.0f;
    To[(long long)na * NH + lane] = (short)__float2int_rn(oA * iA);
    if (lane == 0) rso[na] = mA * ks;
    if (hasB) {
        To[(long long)nb_ * NH + lane] = (short)__float2int_rn(oB * iB);
        if (lane == 0) rso[nb_] = mB * ks;
    }
}

// Layer-1 + fused layer-2 transform for both nodes: z1[c]=di*acc+b1[c];
// t=tanh(z1); t2 = di*(t @ W2) via 6-step full-wave butterfly (per node).
__global__ void __launch_bounds__(256) k_seg1f(
        const short* __restrict__ T, const float* __restrict__ rs,
        const int* __restrict__ esrc, const int* __restrict__ start,
        const int* __restrict__ cnt, const float* __restrict__ dis,
        const float* __restrict__ b1, const float* __restrict__ W2,
        float2* __restrict__ t2, int n) {
    SEG_GATHER2
    float bv = b1[lane];
    float2 w = ((const float2*)W2)[lane];   // W2[lane][0], W2[lane][1]
    float tA = tanhf(dia * accA + bv);
    float p0 = tA * w.x, p1 = tA * w.y;
    float tB = hasB ? tanhf(dib * accB + bv) : 0.0f;
    float q0 = tB * w.x, q1 = tB * w.y;
    #pragma unroll
    for (int msk = 32; msk; msk >>= 1) {
        p0 += __shfl_xor(p0, msk, 64);
        p1 += __shfl_xor(p1, msk, 64);
        q0 += __shfl_xor(q0, msk, 64);
        q1 += __shfl_xor(q1, msk, 64);
    }
    if (lane == 0) {
        t2[na] = make_float2(dia * p0, dia * p1);
        if (hasB) t2[nb_] = make_float2(dib * q0, dib * q1);
    }
}

// Fused layer-2 aggregation + head, 16 LANES PER NODE (4 nodes/wave):
// lane-parallel edge loads (depth ~1 instead of ~16 serial per thread),
// 4-step shfl_xor reduce within the 16-lane group, then lanes 0-3 of the
// group each write 4 of the 16 output channels.
__global__ void __launch_bounds__(256) k_seg2f(
        const float2* __restrict__ T2, const int* __restrict__ esrc,
        const int* __restrict__ start, const int* __restrict__ cnt,
        const float* __restrict__ dis, const float* __restrict__ b2,
        const float* __restrict__ Wc, const float* __restrict__ bc,
        float* __restrict__ out, float* __restrict__ emb, int n) {
    int lane = threadIdx.x & 63;
    int sub = lane >> 4;           // node slot within the wave
    int sl = lane & 15;            // lane within the node's 16-lane group
    int i = blockIdx.x * 16 + (threadIdx.x >> 6) * 4 + sub;
    if (i >= n) return;            // whole 16-lane group exits together
    float di = dis[i];
    int g = cnt[i], st = start[i];
    float a0 = 0.0f, a1 = 0.0f;
    for (int j = sl; j < g; j += 16) {
        float2 v = T2[esrc[st + j]];
        a0 += v.x; a1 += v.y;
    }
    if (sl == 0) {
        float2 s = T2[i];
        a0 += s.x; a1 += s.y;
    }
    #pragma unroll
    for (int msk = 8; msk; msk >>= 1) {
        a0 += __shfl_xor(a0, msk, 64);
        a1 += __shfl_xor(a1, msk, 64);
    }
    float e0 = tanhf(a0 * di + b2[0]);
    float e1 = tanhf(a1 * di + b2[1]);
    if (sl == 0) *(float2*)&emb[(long long)i * 2] = make_float2(e0, e1);
    if (sl < 4) {
        int c = sl * 4;
        float4 o;
        o.x = e0 * Wc[c + 0] + e1 * Wc[16 + c + 0] + bc[c + 0];
        o.y = e0 * Wc[c + 1] + e1 * Wc[16 + c + 1] + bc[c + 1];
        o.z = e0 * Wc[c + 2] + e1 * Wc[16 + c + 2] + bc[c + 2];
        o.w = e0 * Wc[c + 3] + e1 * Wc[16 + c + 3] + bc[c + 3];
        *(float4*)&out[(long long)i * 16 + c] = o;
    }
}

extern "C" void kernel_launch(void* const* d_in, const int* in_sizes, int n_in,
                              void* d_out, int out_size, void* d_ws, size_t ws_size,
                              hipStream_t stream) {
    const float* x  = (const float*)d_in[0];
    const int*   ei = (const int*)  d_in[1];
    const float* W0 = (const float*)d_in[2];
    const float* b0 = (const float*)d_in[3];
    const float* W1 = (const float*)d_in[4];
    const float* b1 = (const float*)d_in[5];
    const float* W2 = (const float*)d_in[6];
    const float* b2 = (const float*)d_in[7];
    const float* Wc = (const float*)d_in[8];
    const float* bc = (const float*)d_in[9];

    int N = in_sizes[0] / NF;
    int E = in_sizes[1] / 2;
    int NB = (N + NPB - 1) / NPB;   // 391 for N=100000 (must be <= MAXNB)

    float* out = (float*)d_out;                    // [N,16]
    float* emb = out + (long long)N * 16;          // [N,2]

    // workspace: T16a[N*64 int16 = 12.8MB] | region2[N*64 fp32 = 25.6MB] |
    //            dis[N] | rs_a[N] | cnt[N] | start[N] | esrc[E] | fmt
    // region2 holds the layer-1 quant row T16b (12.8MB) + t2 (0.8MB) + rs_b
    // (0.4MB). wfrag (32KB W0 MFMA fragments) OVERLAYS the start of region2:
    // written by k_wprep, consumed by k_gemmM, dead before k_seg0t writes
    // T16b there. Preprocessing scratch (~8MB) overlays T16a.
    short*  T16a = (short*)d_ws;
    char*   r2   = (char*)d_ws + (long long)N * NH * 2;
    short*  T16b = (short*)r2;
    short*  wfrag = (short*)r2;                        // 32KB, dead after gemmM
    float2* t2   = (float2*)(r2 + (long long)N * NH * 2);
    float*  rs_b = (float*)(r2 + (long long)N * NH * 2 + (long long)N * 8);
    float*  dis  = (float*)((char*)d_ws + (long long)N * NH * 2 + (long long)N * NH * 4);
    float*  rs_a = dis + N;
    int*    cnt   = (int*)(rs_a + N);
    int*    start = cnt + N;
    int*    esrc  = start + N;
    int*    fmt   = esrc + E;

    int* pairs     = (int*)d_ws;                       // E ints (overlay T16a)
    int* blockbase = pairs + E;                        // A1G * NB
    int* ccnt      = blockbase + (long long)A1G * NB;  // NB*16 (line-padded)
    int* cstart    = ccnt + NB * 16;                   // NB

    int nb_g  = (N + 63) / 64;
    int nb_s2 = (N + 7) / 8;
    int nb_2f = (N + 15) / 16;
    int nb_i0 = (NB * 16 + 255) / 256;

    // W0 fragment precompute (independent of preprocessing)
    k_wprep   <<<16, 256, 0, stream>>>(W0, wfrag);

    // per-call two-level bucket sort (inputs restored before every call)
    k_init0   <<<nb_i0, 256, 0, stream>>>(ei, fmt, ccnt, NB * 16);
    k_coarse  <<<A1G, 256, 0, stream>>>(ei, fmt, ccnt, blockbase, E, NB);
    k_cscan   <<<1, 512, 0, stream>>>(ccnt, cstart, NB);
    k_cscatter<<<A1G, 256, 0, stream>>>(ei, fmt, cstart, blockbase, pairs, E, NB);
    k_bucket  <<<NB, 256, 0, stream>>>(pairs, ccnt, cstart, esrc, cnt, start, dis, N);

    // layer 0: MFMA gemm + rowwise int16 quant
    k_gemmM   <<<nb_g, 256, 0, stream>>>(x, wfrag, dis, T16a, rs_a, N);

    // layer-0 gather + fused layer-1 transform/quant (k_gemm<64> eliminated)
    k_seg0t   <<<nb_s2, 256, 0, stream>>>(T16a, rs_a, esrc, start, cnt, dis, b0,
                                          W1, T16b, rs_b, N);

    // layer 1 gather + fused layer-2 transform (tanh + @W2 in epilogue)
    k_seg1f   <<<nb_s2, 256, 0, stream>>>(T16b, rs_b, esrc, start, cnt, dis, b1,
                                          W2, t2, N);

    // layer-2 aggregation + head (16 lanes per node)
    k_seg2f   <<<nb_2f, 256, 0, stream>>>(t2, esrc, start, cnt, dis, b2, Wc, bc,
                                          out, emb, N);
}

// Round 9
// 303.550 us; speedup vs baseline: 1.1865x; 1.0436x over previous
//
#include <hip/hip_runtime.h>

// GCN forward: 3x GCNConv (128->64->64->2) + linear head (2->16).
// N=100000 nodes, E=1600000 edges (+self-loops handled analytically).
// Preprocessing: two-level LDS bucket sort. Aggregation: atomic-free
// FULL-WAVE segment-sum gathers (lane = channel) over int16 rows with
// per-row scales; TWO nodes per wave interleaved.
// Round 25 (= round 24 resubmit after infra failure, one safety fix):
//  - wf0/wf1 fragment buffers MOVED INTO d_out's first 48KB (out is only
//    written by the final k_seg2f, which overwrites every element; the
//    fragments are consumed by gemmM/gemmM64 well before). Round-24 placed
//    them PAST fmt, growing the workspace footprint -- the only candidate
//    for the observed container page-fault.
//  - k_gemmM DIRECT-LOAD: A-fragments read straight from global (lane's 32B
//    of its row; 4 lanes/line, zero redundancy) -- xs LDS tile + 2 staging
//    barriers + staging VALU deleted. LDS 32KB => 5 blocks/CU, ONE barrier.
//  - seg0t UN-FUSED: k_seg (r2-verified gather, writes h0 fp32 to Bb) +
//    k_gemmM64 (MFMA 64x64 W1 transform). The fused readlane matvec cost
//    ~27us on top of the ~46us gather (1 FMA per ~2 issues vs MFMA's 64).
//    fp32-row ban does NOT apply: Bb is STREAMED (GEMM operand), not
//    randomly gathered.
// MFMA path HW-verified r23 (absmax unchanged 4.88e-4): f16 split-precision
// x=hi+lo, 3 MFMA (hi*whi+hi*wlo+lo*whi), dropped lo*wlo ~2^-24 rel;
// C/D map col=lane&15,row=(lane>>4)*4+reg; same k-map for A and B so
// k-permutation cancels.
// REGIME NOTE (r20 measured): gather kernels are RANDOM-ROW-TRAFFIC bound
// (~1.4-1.8 TB/s fabric on 128B rows); int16 rows ARE the bandwidth opt.
// BANNED (measured failures): half-wave/2-rows-per-load gather (~3e-3 absmax,
// r7-9/11); SGPR-indexed rs[] (s_load thrash, r13); LDS float atomicAdd
// (CAS storm, r15); LDS row pitch not 0 mod 16B in float4 tiles (r17);
// 64-entry per-lane VGPR arrays in gather kernels (occupancy halved, r17);
// persistent grid-stride gather blocks (load imbalance + VGPR, r19);
// fp32 pre-scaled gather rows (2x traffic on traffic-bound GATHER, r20);
// partial LDS staging loops -- verify counts against buffer size (r22);
// growing the workspace footprint past the verified layout (r24).
// dis[] pre-folded: T'[v]=dis[v]*t[v] => O[i]=dis[i]*(T'[i]+sum T'[s])+b.

#define NF 128
#define NH 64
#define NPB 256      // nodes per coarse bucket (bucket = dst >> 8)
#define MAXNB 512    // max coarse buckets (N < 131072, matches 17-bit src pack)
#define CAP 6144     // max edges per coarse bucket (mean 4096, >30 sigma)
#define A1G 1024     // grid for coarse count/scatter (must match between them)

typedef _Float16 half8 __attribute__((ext_vector_type(8)));
typedef float f32x4 __attribute__((ext_vector_type(4)));

// Zero coarse counters + detect int64 vs int32 edge_index layout.
__global__ void k_init0(const int* __restrict__ ei, int* __restrict__ fmt,
                        int* __restrict__ ccnt, int nb16) {
    int i = blockIdx.x * 256 + threadIdx.x;
    if (i < nb16) ccnt[i] = 0;
    if (i == 0) {
        int f = 1;
        #pragma unroll
        for (int k = 1; k < 32; k += 2) if (ei[k] != 0) f = 0;
        *fmt = f;   // 1 => int64 (stride 2 in int32 words), 0 => int32
    }
}

// Coarse count: LDS histogram per block, then reserve per-(block,bucket) space
// with ONE padded global atomic per bucket per block (line-parallel).
__global__ void __launch_bounds__(256) k_coarse(
        const int* __restrict__ ei, const int* __restrict__ fmt,
        int* __restrict__ ccnt, int* __restrict__ blockbase, int E, int NB) {
    __shared__ int h[MAXNB];
    int sh = *fmt;
    for (int i = threadIdx.x; i < NB; i += 256) h[i] = 0;
    __syncthreads();
    for (long long e = (long long)blockIdx.x * 256 + threadIdx.x; e < E;
         e += (long long)A1G * 256) {
        int d = ei[(long long)(E + e) << sh];
        atomicAdd(&h[d >> 8], 1);
    }
    __syncthreads();
    for (int b = threadIdx.x; b < NB; b += 256) {
        int c = h[b];
        int base = (c > 0) ? atomicAdd(&ccnt[b * 16], c) : 0;
        blockbase[(long long)blockIdx.x * NB + b] = base;
    }
}

// Exclusive scan of the NB coarse counts (single block).
__global__ void __launch_bounds__(512) k_cscan(
        const int* __restrict__ ccnt, int* __restrict__ cstart, int NB) {
    __shared__ int s[512];
    int t = threadIdx.x;
    int c = (t < NB) ? ccnt[t * 16] : 0;
    s[t] = c;
    __syncthreads();
    for (int off = 1; off < 512; off <<= 1) {
        int v = s[t];
        int u = (t >= off) ? s[t - off] : 0;
        __syncthreads();
        s[t] = v + u;
        __syncthreads();
    }
    if (t < NB) cstart[t] = s[t] - c;
}

// Coarse scatter: same grid-stride partition as k_coarse, so this block's
// per-bucket totals equal its reservation. Edge packed as src|(dst&255)<<17.
__global__ void __launch_bounds__(256) k_cscatter(
        const int* __restrict__ ei, const int* __restrict__ fmt,
        const int* __restrict__ cstart, const int* __restrict__ blockbase,
        int* __restrict__ pairs, int E, int NB) {
    __shared__ int h[MAXNB];
    __shared__ int bb[MAXNB];
    int sh = *fmt;
    for (int i = threadIdx.x; i < NB; i += 256) {
        h[i] = 0;
        bb[i] = cstart[i] + blockbase[(long long)blockIdx.x * NB + i];
    }
    __syncthreads();
    for (long long e = (long long)blockIdx.x * 256 + threadIdx.x; e < E;
         e += (long long)A1G * 256) {
        int s = ei[(long long)e << sh];
        int d = ei[(long long)(E + e) << sh];
        int b = d >> 8;
        int r = atomicAdd(&h[b], 1);
        pairs[bb[b] + r] = s | ((d & 255) << 17);
    }
}

// Fine sort: one block per coarse bucket, entirely in LDS. Emits cnt/start/dis
// (coalesced) and esrc (scatter within the bucket's contiguous window).
__global__ void __launch_bounds__(256) k_bucket(
        const int* __restrict__ pairs, const int* __restrict__ ccnt,
        const int* __restrict__ cstart, int* __restrict__ esrc,
        int* __restrict__ cnt, int* __restrict__ start, float* __restrict__ dis,
        int N) {
    __shared__ int words[CAP];
    __shared__ unsigned char rk[CAP];
    __shared__ int h[NPB];
    __shared__ int hs[NPB];
    int b = blockIdx.x;
    int cs = cstart[b];
    int ec = ccnt[b * 16];
    if (ec > CAP) ec = CAP;          // memory-safety clamp (P ~ 0 for uniform dst)
    int t = threadIdx.x;
    for (int i = t; i < ec; i += 256) words[i] = pairs[cs + i];
    h[t] = 0;
    __syncthreads();
    for (int i = t; i < ec; i += 256) {
        int ld = words[i] >> 17;
        rk[i] = (unsigned char)atomicAdd(&h[ld], 1);
    }
    __syncthreads();
    int c = h[t];
    hs[t] = c;
    __syncthreads();
    for (int off = 1; off < 256; off <<= 1) {
        int v = hs[t];
        int u = (t >= off) ? hs[t - off] : 0;
        __syncthreads();
        hs[t] = v + u;               // inclusive scan
        __syncthreads();
    }
    int node = b * NPB + t;
    if (node < N) {
        cnt[node] = c;
        start[node] = cs + hs[t] - c;
        dis[node] = rsqrtf(1.0f + (float)c);   // degree includes self-loop
    }
    for (int i = t; i < ec; i += 256) {
        int w = words[i];
        int ld = w >> 17;
        esrc[cs + (hs[ld] - h[ld]) + rk[i]] = w & 0x1FFFF;
    }
}

// Precompute MFMA B-fragments (f16 hi/lo), fragment-ordered so each lane
// reads its 8 halves with one b128.
// Blocks 0-15:  W0 (128x64): kc=b>>2 (0..3), ct=b&3.  wf0: hi 0..8191, lo +8192.
// Blocks 16-23: W1 (64x64):  kc 0..1, ct 0..3.        wf1: hi 0..4095, lo +4096.
// Entry: k = kc*32 + (lane>>4)*8 + j, col = ct*16 + (lane&15).
__global__ void k_wprep(const float* __restrict__ W0, const float* __restrict__ W1,
                        short* __restrict__ wf0, short* __restrict__ wf1) {
    int b = blockIdx.x;
    int t = threadIdx.x;
    int lane = t & 63;
    int j0 = (t >> 6) * 2;
    const float* W = (b < 16) ? W0 : W1;
    int bb = (b < 16) ? b : (b - 16);
    short* wf = (b < 16) ? wf0 : wf1;
    int lohalf = (b < 16) ? 8192 : 4096;
    int kc = bb >> 2, ct = bb & 3;
    #pragma unroll
    for (int jj = 0; jj < 2; ++jj) {
        int j = j0 + jj;
        int k = kc * 32 + (lane >> 4) * 8 + j;
        int col = ct * 16 + (lane & 15);
        float w = W[k * NH + col];
        _Float16 h = (_Float16)w;
        _Float16 l = (_Float16)(w - (float)h);
        int idx = (bb * 64 + lane) * 8 + j;
        wf[idx] = *(short*)&h;
        wf[idx + lohalf] = *(short*)&l;
    }
}

// Shared MFMA epilogue: dis-scale + rowwise int16 quant + store.
// Lane holds D[(lane>>4)*4 + r][ct*16 + (lane&15)] for ct=0..3 (m89 map).
#define GEMM_EPILOGUE                                                         \
    int rb = (int)rowbase + wid * 16 + (lane >> 4) * 4;                       \
    float drs[4];                                                             \
    drs[0] = (rb + 0 < n) ? dis[rb + 0] : 0.0f;                               \
    drs[1] = (rb + 1 < n) ? dis[rb + 1] : 0.0f;                               \
    drs[2] = (rb + 2 < n) ? dis[rb + 2] : 0.0f;                               \
    drs[3] = (rb + 3 < n) ? dis[rb + 3] : 0.0f;                               \
    const float ks = 1.0f / 32767.0f;                                         \
    int cb = lane & 15;                                                       \
    _Pragma("unroll")                                                         \
    for (int r = 0; r < 4; ++r) {                                             \
        float v0 = acc0[r] * drs[r];                                          \
        float v1 = acc1[r] * drs[r];                                          \
        float v2 = acc2[r] * drs[r];                                          \
        float v3 = acc3[r] * drs[r];                                          \
        float m = fmaxf(fmaxf(fabsf(v0), fabsf(v1)), fmaxf(fabsf(v2), fabsf(v3))); \
        m = fmaxf(m, __shfl_xor(m, 1, 64));                                   \
        m = fmaxf(m, __shfl_xor(m, 2, 64));                                   \
        m = fmaxf(m, __shfl_xor(m, 4, 64));                                   \
        m = fmaxf(m, __shfl_xor(m, 8, 64));                                   \
        float ir = 32767.0f / fmaxf(m, 1e-20f);                               \
        int rowg = rb + r;                                                    \
        if (rowg < n) {                                                       \
            long long base = (long long)rowg * NH;                            \
            T16[base + 0  + cb] = (short)__float2int_rn(v0 * ir);             \
            T16[base + 16 + cb] = (short)__float2int_rn(v1 * ir);             \
            T16[base + 32 + cb] = (short)__float2int_rn(v2 * ir);             \
            T16[base + 48 + cb] = (short)__float2int_rn(v3 * ir);             \
            if (cb == 0) rs[rowg] = m * ks;                                   \
        }                                                                     \
    }

// Convert lane's 8 A-floats to f16 hi/lo fragments.
#define CVT_AFRAG(xa, xb4)                                                    \
    half8 ah, al;                                                             \
    {                                                                         \
        float xv[8] = {xa.x, xa.y, xa.z, xa.w, xb4.x, xb4.y, xb4.z, xb4.w};   \
        _Pragma("unroll")                                                     \
        for (int e = 0; e < 8; ++e) {                                         \
            _Float16 h = (_Float16)xv[e];                                     \
            ah[e] = h;                                                        \
            al[e] = (_Float16)(xv[e] - (float)h);                             \
        }                                                                     \
    }

#define MFMA3(ACC, SETIDX, LOHALF)                                            \
    {                                                                         \
        const half8 bh = *(const half8*)&Wf[((SETIDX) * 64 + lane) * 8];      \
        const half8 bl = *(const half8*)&Wf[((SETIDX) * 64 + lane) * 8 + (LOHALF)]; \
        ACC = __builtin_amdgcn_mfma_f32_16x16x32_f16(ah, bh, ACC, 0, 0, 0);   \
        ACC = __builtin_amdgcn_mfma_f32_16x16x32_f16(ah, bl, ACC, 0, 0, 0);   \
        ACC = __builtin_amdgcn_mfma_f32_16x16x32_f16(al, bh, ACC, 0, 0, 0);   \
    }

// Layer-0 transform on MATRIX CORES, DIRECT-LOAD A: T16 = quant(dis*(X@W0)).
// 64 rows/block, 4 waves, 16 rows/wave; lane reads its 32B A-slice per kc
// straight from global (4 lanes share each 128B line; X read exactly once).
// LDS = Wf only (32KB = 2048 int4, staged once) => 5 blocks/CU, ONE barrier.
__global__ void __launch_bounds__(256) k_gemmM(
        const float* __restrict__ X, const short* __restrict__ wfrag,
        const float* __restrict__ dis, short* __restrict__ T16,
        float* __restrict__ rs, int n) {
    __shared__ __align__(16) short Wf[16384];   // [hi 8192][lo 8192]
    int tid = threadIdx.x;
    {
        const int4* src = (const int4*)wfrag;
        int4* dst = (int4*)Wf;
        #pragma unroll
        for (int u = 0; u < 8; ++u) dst[tid + u * 256] = src[tid + u * 256];
    }
    __syncthreads();
    long long rowbase = (long long)blockIdx.x * 64;
    int lane = tid & 63;
    int wid = tid >> 6;
    int row = (int)rowbase + wid * 16 + (lane & 15);
    bool ok = row < n;
    const float* xb = X + (long long)row * NF + (lane >> 4) * 8;
    f32x4 acc0 = {0,0,0,0}, acc1 = {0,0,0,0}, acc2 = {0,0,0,0}, acc3 = {0,0,0,0};
    #pragma unroll
    for (int kc = 0; kc < 4; ++kc) {
        float4 xa = ok ? *(const float4*)(xb + kc * 32)
                       : make_float4(0.f, 0.f, 0.f, 0.f);
        float4 xc = ok ? *(const float4*)(xb + kc * 32 + 4)
                       : make_float4(0.f, 0.f, 0.f, 0.f);
        CVT_AFRAG(xa, xc)
        MFMA3(acc0, kc * 4 + 0, 8192)
        MFMA3(acc1, kc * 4 + 1, 8192)
        MFMA3(acc2, kc * 4 + 2, 8192)
        MFMA3(acc3, kc * 4 + 3, 8192)
    }
    GEMM_EPILOGUE
}

// Layer-1 transform on MATRIX CORES: T16 = quant(dis*(H0@W1)), H0 fp32 [N,64]
// streamed (coalesced GEMM operand -- r20's random-gather fp32 ban N/A).
// 24 MFMA/wave; LDS = Wf1 16KB (1024 int4).
__global__ void __launch_bounds__(256) k_gemmM64(
        const float* __restrict__ H, const short* __restrict__ wfrag,
        const float* __restrict__ dis, short* __restrict__ T16,
        float* __restrict__ rs, int n) {
    __shared__ __align__(16) short Wf[8192];    // [hi 4096][lo 4096]
    int tid = threadIdx.x;
    {
        const int4* src = (const int4*)wfrag;
        int4* dst = (int4*)Wf;
        #pragma unroll
        for (int u = 0; u < 4; ++u) dst[tid + u * 256] = src[tid + u * 256];
    }
    __syncthreads();
    long long rowbase = (long long)blockIdx.x * 64;
    int lane = tid & 63;
    int wid = tid >> 6;
    int row = (int)rowbase + wid * 16 + (lane & 15);
    bool ok = row < n;
    const float* hb = H + (long long)row * NH + (lane >> 4) * 8;
    f32x4 acc0 = {0,0,0,0}, acc1 = {0,0,0,0}, acc2 = {0,0,0,0}, acc3 = {0,0,0,0};
    #pragma unroll
    for (int kc = 0; kc < 2; ++kc) {
        float4 xa = ok ? *(const float4*)(hb + kc * 32)
                       : make_float4(0.f, 0.f, 0.f, 0.f);
        float4 xc = ok ? *(const float4*)(hb + kc * 32 + 4)
                       : make_float4(0.f, 0.f, 0.f, 0.f);
        CVT_AFRAG(xa, xc)
        MFMA3(acc0, kc * 4 + 0, 4096)
        MFMA3(acc1, kc * 4 + 1, 4096)
        MFMA3(acc2, kc * 4 + 2, 4096)
        MFMA3(acc3, kc * 4 + 3, 4096)
    }
    GEMM_EPILOGUE
}

// One A-edge / B-edge step: readlane word+scale bits, saddr int16 load, fma.
#define EDGE_A(J) {                                                           \
    int s_ = __builtin_amdgcn_readlane(sA, (J));                              \
    float f_ = __int_as_float(__builtin_amdgcn_readlane(fAb, (J)));           \
    accA = fmaf(f_, (float)(T + s_ * NH)[lane], accA); }
#define EDGE_B(J) {                                                           \
    int s_ = __builtin_amdgcn_readlane(sB, (J));                              \
    float f_ = __int_as_float(__builtin_amdgcn_readlane(fBb, (J)));           \
    accB = fmaf(f_, (float)(T + s_ * NH)[lane], accB); }

// Full-wave gather, TWO nodes per wave (A,B) with interleaved batches:
// the two batch prologues (esrc load + rs vector-gather) are independent
// chains and overlap; inner loop interleaves 4 A-edges + 4 B-edges.
#define SEG_GATHER2                                                           \
    int lane = threadIdx.x & 63;                                              \
    int na = blockIdx.x * 8 + (threadIdx.x >> 6) * 2;                         \
    int nb_ = na + 1;                                                         \
    if (na >= n) return;                                                      \
    bool hasB = (nb_ < n);                                                    \
    float dia = dis[na];                                                      \
    float dib = hasB ? dis[nb_] : 0.0f;                                       \
    int ga = cnt[na], sta = start[na];                                        \
    int gb = hasB ? cnt[nb_] : 0;                                             \
    int stb = hasB ? start[nb_] : 0;                                          \
    float accA = rs[na] * (float)T[na * NH + lane];                           \
    float accB = hasB ? rs[nb_] * (float)T[nb_ * NH + lane] : 0.0f;           \
    int gmax = ga > gb ? ga : gb;                                             \
    for (int base = 0; base < gmax; base += 64) {                             \
        int ma = ga - base; ma = ma < 0 ? 0 : (ma > 64 ? 64 : ma);            \
        int mb = gb - base; mb = mb < 0 ? 0 : (mb > 64 ? 64 : mb);            \
        int sA = 0, sB = 0; float fA = 0.0f, fB = 0.0f;                       \
        if (lane < ma) { sA = esrc[sta + base + lane]; fA = rs[sA]; }         \
        if (lane < mb) { sB = esrc[stb + base + lane]; fB = rs[sB]; }         \
        int fAb = __float_as_int(fA), fBb = __float_as_int(fB);               \
        int mmin = ma < mb ? ma : mb;                                         \
        int j = 0;                                                            \
        for (; j + 3 < mmin; j += 4) {                                        \
            EDGE_A(j + 0) EDGE_B(j + 0)                                       \
            EDGE_A(j + 1) EDGE_B(j + 1)                                       \
            EDGE_A(j + 2) EDGE_B(j + 2)                                       \
            EDGE_A(j + 3) EDGE_B(j + 3)                                       \
        }                                                                     \
        int jA = j, jB = j;                                                   \
        for (; jA + 3 < ma; jA += 4) {                                        \
            EDGE_A(jA + 0) EDGE_A(jA + 1) EDGE_A(jA + 2) EDGE_A(jA + 3)       \
        }                                                                     \
        for (; jA < ma; ++jA) EDGE_A(jA)                                      \
        for (; jB + 3 < mb; jB += 4) {                                        \
            EDGE_B(jB + 0) EDGE_B(jB + 1) EDGE_B(jB + 2) EDGE_B(jB + 3)       \
        }                                                                     \
        for (; jB < mb; ++jB) EDGE_B(jB)                                      \
    }

// Layer-0 aggregation: h0 = dia*acc + b0 written as fp32 (streamed GEMM
// operand for k_gemmM64). r2-verified form (~46us, VALUBusy 73%, occ 72%).
__global__ void __launch_bounds__(256) k_seg(
        const short* __restrict__ T, const float* __restrict__ rs,
        const int* __restrict__ esrc, const int* __restrict__ start,
        const int* __restrict__ cnt, const float* __restrict__ dis,
        const float* __restrict__ b0, float* __restrict__ O, int n) {
    SEG_GATHER2
    float bv = b0[lane];
    O[(long long)na * NH + lane] = dia * accA + bv;
    if (hasB) O[(long long)nb_ * NH + lane] = dib * accB + bv;
}

// Layer-1 + fused layer-2 transform for both nodes: z1[c]=di*acc+b1[c];
// t=tanh(z1); t2 = di*(t @ W2) via 6-step full-wave butterfly (per node).
__global__ void __launch_bounds__(256) k_seg1f(
        const short* __restrict__ T, const float* __restrict__ rs,
        const int* __restrict__ esrc, const int* __restrict__ start,
        const int* __restrict__ cnt, const float* __restrict__ dis,
        const float* __restrict__ b1, const float* __restrict__ W2,
        float2* __restrict__ t2, int n) {
    SEG_GATHER2
    float bv = b1[lane];
    float2 w = ((const float2*)W2)[lane];   // W2[lane][0], W2[lane][1]
    float tA = tanhf(dia * accA + bv);
    float p0 = tA * w.x, p1 = tA * w.y;
    float tB = hasB ? tanhf(dib * accB + bv) : 0.0f;
    float q0 = tB * w.x, q1 = tB * w.y;
    #pragma unroll
    for (int msk = 32; msk; msk >>= 1) {
        p0 += __shfl_xor(p0, msk, 64);
        p1 += __shfl_xor(p1, msk, 64);
        q0 += __shfl_xor(q0, msk, 64);
        q1 += __shfl_xor(q1, msk, 64);
    }
    if (lane == 0) {
        t2[na] = make_float2(dia * p0, dia * p1);
        if (hasB) t2[nb_] = make_float2(dib * q0, dib * q1);
    }
}

// Fused layer-2 aggregation + head, 16 LANES PER NODE (4 nodes/wave):
// lane-parallel edge loads, 4-step shfl_xor reduce, lanes 0-3 write the
// 16 output channels.
__global__ void __launch_bounds__(256) k_seg2f(
        const float2* __restrict__ T2, const int* __restrict__ esrc,
        const int* __restrict__ start, const int* __restrict__ cnt,
        const float* __restrict__ dis, const float* __restrict__ b2,
        const float* __restrict__ Wc, const float* __restrict__ bc,
        float* __restrict__ out, float* __restrict__ emb, int n) {
    int lane = threadIdx.x & 63;
    int sub = lane >> 4;           // node slot within the wave
    int sl = lane & 15;            // lane within the node's 16-lane group
    int i = blockIdx.x * 16 + (threadIdx.x >> 6) * 4 + sub;
    if (i >= n) return;            // whole 16-lane group exits together
    float di = dis[i];
    int g = cnt[i], st = start[i];
    float a0 = 0.0f, a1 = 0.0f;
    for (int j = sl; j < g; j += 16) {
        float2 v = T2[esrc[st + j]];
        a0 += v.x; a1 += v.y;
    }
    if (sl == 0) {
        float2 s = T2[i];
        a0 += s.x; a1 += s.y;
    }
    #pragma unroll
    for (int msk = 8; msk; msk >>= 1) {
        a0 += __shfl_xor(a0, msk, 64);
        a1 += __shfl_xor(a1, msk, 64);
    }
    float e0 = tanhf(a0 * di + b2[0]);
    float e1 = tanhf(a1 * di + b2[1]);
    if (sl == 0) *(float2*)&emb[(long long)i * 2] = make_float2(e0, e1);
    if (sl < 4) {
        int c = sl * 4;
        float4 o;
        o.x = e0 * Wc[c + 0] + e1 * Wc[16 + c + 0] + bc[c + 0];
        o.y = e0 * Wc[c + 1] + e1 * Wc[16 + c + 1] + bc[c + 1];
        o.z = e0 * Wc[c + 2] + e1 * Wc[16 + c + 2] + bc[c + 2];
        o.w = e0 * Wc[c + 3] + e1 * Wc[16 + c + 3] + bc[c + 3];
        *(float4*)&out[(long long)i * 16 + c] = o;
    }
}

extern "C" void kernel_launch(void* const* d_in, const int* in_sizes, int n_in,
                              void* d_out, int out_size, void* d_ws, size_t ws_size,
                              hipStream_t stream) {
    const float* x  = (const float*)d_in[0];
    const int*   ei = (const int*)  d_in[1];
    const float* W0 = (const float*)d_in[2];
    const float* b0 = (const float*)d_in[3];
    const float* W1 = (const float*)d_in[4];
    const float* b1 = (const float*)d_in[5];
    const float* W2 = (const float*)d_in[6];
    const float* b2 = (const float*)d_in[7];
    const float* Wc = (const float*)d_in[8];
    const float* bc = (const float*)d_in[9];

    int N = in_sizes[0] / NF;
    int E = in_sizes[1] / 2;
    int NB = (N + NPB - 1) / NPB;   // 391 for N=100000 (must be <= MAXNB)

    float* out = (float*)d_out;                    // [N,16]
    float* emb = out + (long long)N * 16;          // [N,2]

    // workspace (UNCHANGED footprint vs verified rounds):
    //   T16a[N*64 int16 = 12.8MB] | Bb[N*64 fp32 = 25.6MB] |
    //   dis[N] | rs_a[N] | cnt[N] | start[N] | esrc[E] | fmt
    // wf0 (32KB) + wf1 (16KB) live at the START OF d_out: out is written
    // only by the final k_seg2f (which overwrites every element); fragments
    // are consumed by gemmM/gemmM64 before that. Zero footprint growth.
    // Flow: gemmM: x->T16a.  k_seg: T16a->Bb (h0).  gemmM64: Bb->T16a.
    // seg1f: T16a->t2 (t2 overlays dead Bb).  Prep scratch overlays T16a.
    short*  T16a = (short*)d_ws;
    float*  Bb   = (float*)((char*)d_ws + (long long)N * NH * 2);
    float*  dis  = (float*)((char*)d_ws + (long long)N * NH * 2 + (long long)N * NH * 4);
    float*  rs_a = dis + N;
    int*    cnt   = (int*)(rs_a + N);
    int*    start = cnt + N;
    int*    esrc  = start + N;
    int*    fmt   = esrc + E;
    short*  wf0   = (short*)d_out;                 // 16384 shorts (32KB)
    short*  wf1   = wf0 + 16384;                   // 8192 shorts (16KB)
    float2* t2    = (float2*)Bb;                   // overlays dead Bb

    int* pairs     = (int*)d_ws;                       // E ints (overlay T16a)
    int* blockbase = pairs + E;                        // A1G * NB
    int* ccnt      = blockbase + (long long)A1G * NB;  // NB*16 (line-padded)
    int* cstart    = ccnt + NB * 16;                   // NB

    int nb_g  = (N + 63) / 64;
    int nb_s2 = (N + 7) / 8;
    int nb_2f = (N + 15) / 16;
    int nb_i0 = (NB * 16 + 255) / 256;

    // W0+W1 fragment precompute (independent of preprocessing)
    k_wprep   <<<24, 256, 0, stream>>>(W0, W1, wf0, wf1);

    // per-call two-level bucket sort (inputs restored before every call)
    k_init0   <<<nb_i0, 256, 0, stream>>>(ei, fmt, ccnt, NB * 16);
    k_coarse  <<<A1G, 256, 0, stream>>>(ei, fmt, ccnt, blockbase, E, NB);
    k_cscan   <<<1, 512, 0, stream>>>(ccnt, cstart, NB);
    k_cscatter<<<A1G, 256, 0, stream>>>(ei, fmt, cstart, blockbase, pairs, E, NB);
    k_bucket  <<<NB, 256, 0, stream>>>(pairs, ccnt, cstart, esrc, cnt, start, dis, N);

    // layer 0: MFMA gemm (direct-load A) + rowwise int16 quant
    k_gemmM   <<<nb_g, 256, 0, stream>>>(x, wf0, dis, T16a, rs_a, N);

    // layer-0 gather -> h0 fp32 (streamed operand)
    k_seg     <<<nb_s2, 256, 0, stream>>>(T16a, rs_a, esrc, start, cnt, dis, b0,
                                          Bb, N);

    // layer-1 transform: MFMA gemm64 (Bb -> T16a, rs_a overwritten)
    k_gemmM64 <<<nb_g, 256, 0, stream>>>(Bb, wf1, dis, T16a, rs_a, N);

    // layer 1 gather + fused layer-2 transform (tanh + @W2 in epilogue)
    k_seg1f   <<<nb_s2, 256, 0, stream>>>(T16a, rs_a, esrc, start, cnt, dis, b1,
                                          W2, t2, N);

    // layer-2 aggregation + head (16 lanes per node)
    k_seg2f   <<<nb_2f, 256, 0, stream>>>(t2, esrc, start, cnt, dis, b2, Wc, bc,
                                          out, emb, N);
}